// Round 7
// baseline (200.530 us; speedup 1.0000x reference)
//
#include <hip/hip_runtime.h>

// B=4, H=8, Nt=Nc=2048, D=512, E=64, scale = 1/64 folded into Wq at cast.
#define B_   4
#define H_   8
#define NSEQ 2048
#define D_   512
#define E_   64

typedef __bf16 bf16x8 __attribute__((ext_vector_type(8)));
typedef float  f32x4  __attribute__((ext_vector_type(4)));
typedef float  f32x16 __attribute__((ext_vector_type(16)));

__device__ __forceinline__ unsigned short f2b(float f) {
    __bf16 h = (__bf16)f;                     // RNE
    return __builtin_bit_cast(unsigned short, h);
}
__device__ __forceinline__ unsigned pk2(float a, float b) {
    return (unsigned)f2b(a) | ((unsigned)f2b(b) << 16);
}
__device__ __forceinline__ bf16x8 ld_frag(const unsigned short* p) {
    return *reinterpret_cast<const bf16x8*>(p);
}
// async global->LDS, 16B per lane: LDS dest = wave-uniform base + lane*16.
__device__ __forceinline__ void async_copy16(const void* g, const unsigned short* l) {
    __builtin_amdgcn_global_load_lds(
        (const __attribute__((address_space(1))) unsigned int*)g,
        (__attribute__((address_space(3))) unsigned int*)l, 16, 0, 0);
}

// ---------------------------------------------------------------------------
// Interleaved-2 LDS tile layout for 128-B rows (conflict-free b128 reads).
// 16B block (r, s) [s = 0..7] -> lr = r>>1; phys = (((r&1)<<3)|s) ^ (lr&15).
// ---------------------------------------------------------------------------
__device__ __forceinline__ int lds_blk(int r, int s) {
    int lr = r >> 1;
    return lr * 128 + (((((r & 1) << 3) | s) ^ (lr & 15)) << 3);  // ushort idx
}
#define STAGE_SRC(r0, l, row, slot)                                            \
    {   int lr_ = ((r0) >> 1) + ((l) >> 4);                                    \
        int B_x = ((l) & 15) ^ (lr_ & 15);                                     \
        row = (lr_ << 1) | (B_x >> 3);  slot = B_x & 7; }
// 256-B rows (16 slots): phys slot = s ^ (r&15)
__device__ __forceinline__ int lds_blkV(int r, int s) {
    return r * 128 + ((s ^ (r & 15)) << 3);                       // ushort idx
}

// ---------------------------------------------------------------------------
// Cast + transpose W: [H][D][E] fp32 -> [he][d] bf16 (y=0..2); Wout (y=3).
// Wq (y=2) pre-scaled by 1/64 (exact exponent shift).
// ---------------------------------------------------------------------------
__global__ __launch_bounds__(256)
void cast_w_kernel(const float* __restrict__ Wk, const float* __restrict__ Wv,
                   const float* __restrict__ Wq, const float* __restrict__ Wo,
                   unsigned short* __restrict__ okt, unsigned short* __restrict__ ovt,
                   unsigned short* __restrict__ oqt, unsigned short* __restrict__ oo) {
    int idx = blockIdx.x * 256 + threadIdx.x;   // < 262144
    int y = blockIdx.y;
    if (y == 3) { oo[idx] = f2b(Wo[idx]); return; }
    const float* src = y == 0 ? Wk : (y == 1 ? Wv : Wq);
    unsigned short* dst = y == 0 ? okt : (y == 1 ? ovt : oqt);
    float scl = (y == 2) ? 0.015625f : 1.0f;
    int hh = idx >> 15, rem = idx & 32767, d = rem >> 6, e = rem & 63;
    dst[hh * 32768 + e * 512 + d] = f2b(src[idx] * scl);   // [(h*64+e)][d]
}

// ---------------------------------------------------------------------------
// X cast: fp32 [8192][512] -> bf16 [8192][512], y selects q/k/v.
// ---------------------------------------------------------------------------
__global__ __launch_bounds__(256)
void xcast_kernel(const float* __restrict__ q, const float* __restrict__ k,
                  const float* __restrict__ v,
                  unsigned short* __restrict__ qx, unsigned short* __restrict__ kx,
                  unsigned short* __restrict__ vx) {
    const int y = blockIdx.y;
    const float* src = y == 0 ? q : (y == 1 ? k : v);
    unsigned short* dst = y == 0 ? qx : (y == 1 ? kx : vx);
    #pragma unroll
    for (int i = 0; i < 4; ++i) {
        int e = blockIdx.x * 4096 + i * 1024 + threadIdx.x * 4;
        float4 f = *reinterpret_cast<const float4*>(src + e);
        *reinterpret_cast<ushort4*>(dst + e) =
            make_ushort4(f2b(f.x), f2b(f.y), f2b(f.z), f2b(f.w));
    }
}

// ---------------------------------------------------------------------------
// Projection NT-GEMM (pure bf16): C[m][he] = sum_d X[m][d]*Wt[he][d].
// 8192x512x512, which: 0=Q 1=K 2=V. 128x64 tile, BK=64. (FROZEN control)
// ---------------------------------------------------------------------------
__global__ __launch_bounds__(256, 3)
void proj_gemm(const unsigned short* __restrict__ qx,
               const unsigned short* __restrict__ kx,
               const unsigned short* __restrict__ vx,
               const unsigned short* __restrict__ wqt,
               const unsigned short* __restrict__ wkt,
               const unsigned short* __restrict__ wvt,
               unsigned short* __restrict__ qb, unsigned short* __restrict__ kb,
               unsigned short* __restrict__ vtb) {
    const int m0  = blockIdx.x * 128;
    const int no0 = blockIdx.y * 64;
    const int which = blockIdx.z;
    const int tid = threadIdx.x;
    const int wave = tid >> 6, lane = tid & 63;
    const int quad = lane >> 4, l16 = lane & 15;

    const unsigned short* X = which == 0 ? qx : (which == 1 ? kx : vx);
    const unsigned short* W = which == 0 ? wqt : (which == 1 ? wkt : wvt);

    __shared__ unsigned short Ab[2][8192];   // 2 x 16 KB (128 rows x 128 B)
    __shared__ unsigned short Bb[2][4096];   // 2 x  8 KB ( 64 rows x 128 B)

    const unsigned short* Xp = X + (size_t)m0 * D_;
    const unsigned short* Wp = W + (size_t)no0 * D_;

    int rowA[4], slA[4], rowB[2], slB[2];
    #pragma unroll
    for (int i = 0; i < 4; ++i) STAGE_SRC(wave * 32 + i * 8, lane, rowA[i], slA[i])
    #pragma unroll
    for (int i = 0; i < 2; ++i) STAGE_SRC(wave * 16 + i * 8, lane, rowB[i], slB[i])

    #define PROJ_STAGE(kt, buf)                                                \
        {   _Pragma("unroll")                                                  \
            for (int i = 0; i < 4; ++i)                                        \
                async_copy16(Xp + (size_t)rowA[i] * D_ + (kt) * 64 + slA[i] * 8, \
                             &Ab[buf][(wave * 32 + i * 8) * 64]);              \
            _Pragma("unroll")                                                  \
            for (int i = 0; i < 2; ++i)                                        \
                async_copy16(Wp + (size_t)rowB[i] * D_ + (kt) * 64 + slB[i] * 8, \
                             &Bb[buf][(wave * 16 + i * 8) * 64]);              \
        }

    PROJ_STAGE(0, 0)
    __syncthreads();                          // vmcnt drain: tile 0 resident

    const f32x4 z = {0.f, 0.f, 0.f, 0.f};
    f32x4 acc[2][4];
    #pragma unroll
    for (int i = 0; i < 2; ++i)
        #pragma unroll
        for (int j = 0; j < 4; ++j) acc[i][j] = z;

    for (int kt = 0; kt < 8; ++kt) {
        const int cur = kt & 1;
        if (kt + 1 < 8) PROJ_STAGE(kt + 1, 1 - cur)   // in flight over compute
        #pragma unroll
        for (int kk = 0; kk < 2; ++kk) {
            const int s = kk * 4 + quad;      // 16B slot of this k-octet
            bf16x8 bfr[4];
            #pragma unroll
            for (int nt = 0; nt < 4; ++nt)
                bfr[nt] = ld_frag(&Bb[cur][lds_blk(nt * 16 + l16, s)]);
            #pragma unroll
            for (int mt = 0; mt < 2; ++mt) {
                bf16x8 af = ld_frag(&Ab[cur][lds_blk(wave * 32 + mt * 16 + l16, s)]);
                #pragma unroll
                for (int nt = 0; nt < 4; ++nt)
                    acc[mt][nt] = __builtin_amdgcn_mfma_f32_16x16x32_bf16(
                        af, bfr[nt], acc[mt][nt], 0, 0, 0);
            }
        }
        __syncthreads();                      // drains vmcnt (tile kt+1) + lgkm
    }

    // epilogue: overlay staging on Ab (32 KB contiguous)
    if (which != 2) {
        unsigned short (*Os)[72] = reinterpret_cast<unsigned short(*)[72]>(&Ab[0][0]);
        #pragma unroll
        for (int mt = 0; mt < 2; ++mt)
            #pragma unroll
            for (int nt = 0; nt < 4; ++nt)
                #pragma unroll
                for (int r = 0; r < 4; ++r)
                    Os[wave * 32 + mt * 16 + quad * 4 + r][nt * 16 + l16] =
                        f2b(acc[mt][nt][r]);
        __syncthreads();
        unsigned short* Y = (which == 0 ? qb : kb);
        #pragma unroll
        for (int i = 0; i < 4; ++i) {           // 128 rows x 8 uint4
            int idx = tid + i * 256;
            int row = idx >> 3, seg = idx & 7;
            *reinterpret_cast<uint4*>(Y + (size_t)(m0 + row) * D_ + no0 + seg * 8) =
                *reinterpret_cast<const uint4*>(&Os[row][seg * 8]);
        }
    } else {
        unsigned short (*Ot)[136] = reinterpret_cast<unsigned short(*)[136]>(&Ab[0][0]);
        #pragma unroll
        for (int mt = 0; mt < 2; ++mt)
            #pragma unroll
            for (int nt = 0; nt < 4; ++nt) {
                ushort4 o = make_ushort4(f2b(acc[mt][nt][0]), f2b(acc[mt][nt][1]),
                                         f2b(acc[mt][nt][2]), f2b(acc[mt][nt][3]));
                *reinterpret_cast<ushort4*>(
                    &Ot[nt * 16 + l16][wave * 32 + mt * 16 + quad * 4]) = o;
            }
        __syncthreads();
        const int b = m0 >> 11, nloc = m0 & 2047;
        #pragma unroll
        for (int i = 0; i < 4; ++i) {           // 64 he-rows x 16 uint4
            int idx = tid + i * 256;
            int lhe = idx >> 4, seg = idx & 15;
            int ghe = no0 + lhe;                 // h = ghe>>6, e = ghe&63
            *reinterpret_cast<uint4*>(
                vtb + ((size_t)(b * H_ + (ghe >> 6)) * E_ + (ghe & 63)) * NSEQ +
                nloc + seg * 8) =
                *reinterpret_cast<const uint4*>(&Ot[lhe][seg * 8]);
        }
    }
    #undef PROJ_STAGE
}

// ---------------------------------------------------------------------------
// Flash attention, 32x32x16 MFMA, in-register P, 128-KEY TILES.
// 64-row Q tiles (grid 1024), 256 threads = 4 waves; wave w owns key-quarter
// [w*32, w*32+32) of each 128-key tile and handles ALL 64 q (two 32-q MFMA
// chains share every K/V fragment read -> no wq duplication; DS reads and
// barriers both halve per unit work vs 64-key tiles).
//   S = mfma(K, Q[qh]) x2 ; P = exp(S) in regs; permlane32_swap -> PV B-op;
//   O-partial[64e][64q] per wave over its 32 keys; 4-way combine + l-norm
//   in an epilogue through an LDS overlay. m=0 softmax, deferred l.
// LDS: K dbuf 2x16KB (interleaved-2) + V^T dbuf 2x16KB (xor-16, 256B rows)
//  + epilogue overlay [4][64 q][66 e] f32 + Ls[4][64]  => 68,608 B, 2 blk/CU.
// ---------------------------------------------------------------------------
__global__ __launch_bounds__(256, 2)
void attn_kernel(const unsigned short* __restrict__ qbp,
                 const unsigned short* __restrict__ kbp,
                 const unsigned short* __restrict__ vtbp,
                 unsigned short* __restrict__ aob) {
    const int L = blockIdx.x;
    const int bh = L & 31, qt = L >> 5;      // L%8 pattern -> XCD K/V affinity
    const int b = bh >> 3, h = bh & 7;
    const int n0 = qt * 64;
    const int tid = threadIdx.x;
    const int wave = tid >> 6, lane = tid & 63;
    const int l32 = lane & 31, hi = lane >> 5;

    __shared__ unsigned short SM[34304];               // 68,608 B
    unsigned short* Ksm = SM;                          // [2][128 r][64 d] il-2
    unsigned short* Vsm = SM + 16384;                  // [2][64 e][128 k] xor16
    float* Op = reinterpret_cast<float*>(SM);          // epi overlay [4][64][66]
    float* Ls = reinterpret_cast<float*>(SM + 33792);  // epi [4][64]

    const unsigned short* kbase = kbp + (size_t)(b * NSEQ) * D_ + h * 64;
    const unsigned short* vbase = vtbp + (size_t)(b * H_ + h) * E_ * NSEQ;

    // loop-invariant staging sources
    int rowK[4], slK[4];                     // K: 4 slabs of 8 rows (128B rows)
    #pragma unroll
    for (int i = 0; i < 4; ++i) STAGE_SRC(wave * 32 + i * 8, lane, rowK[i], slK[i])
    int rowV[4], slV[4];                     // V: 4 slabs of 4 rows (256B rows)
    #pragma unroll
    for (int i = 0; i < 4; ++i) {
        int r = wave * 16 + i * 4 + (lane >> 4);
        rowV[i] = r; slV[i] = (lane & 15) ^ (r & 15);
    }

    // Q B-frags for BOTH q-halves (lane&31 = q col, k-octet = hi)
    bf16x8 qf[2][4];
    #pragma unroll
    for (int qh = 0; qh < 2; ++qh)
        #pragma unroll
        for (int ks = 0; ks < 4; ++ks)
            qf[qh][ks] = ld_frag(
                qbp + (size_t)(b * NSEQ + n0 + qh * 32 + l32) * D_ +
                h * 64 + ks * 16 + hi * 8);

    #define ATTN_STAGE(j, buf)                                                 \
        {   _Pragma("unroll")                                                  \
            for (int i = 0; i < 4; ++i) {                                      \
                async_copy16(                                                  \
                    kbase + (size_t)((j) * 128 + rowK[i]) * D_ + slK[i] * 8,   \
                    Ksm + (buf) * 8192 + (wave * 32 + i * 8) * 64);            \
                async_copy16(                                                  \
                    vbase + (size_t)rowV[i] * NSEQ + (j) * 128 + slV[i] * 8,   \
                    Vsm + (buf) * 8192 + (wave * 16 + i * 4) * 128);           \
            } }

    ATTN_STAGE(0, 0)
    __syncthreads();                            // vmcnt drain: tile 0 resident

    f32x16 oacc[2][2] = {};                     // [qh][eb], own 32 keys
    float lacc0 = 0.f, lacc1 = 0.f;

    for (int j = 0; j < NSEQ / 128; ++j) {
        const int cur = j & 1;
        if (j + 1 < NSEQ / 128) ATTN_STAGE(j + 1, 1 - cur)  // in flight over compute

        const unsigned short* Kc = Ksm + cur * 8192;
        const unsigned short* Vc = Vsm + cur * 8192;

        // S = mfma(K, Q): A = K[key = wave*32 + l32][octet ks*2 + hi];
        // ONE K read feeds both q-half MFMAs.
        f32x16 s0 = {}, s1 = {};
        #pragma unroll
        for (int ks = 0; ks < 4; ++ks) {
            bf16x8 kf = ld_frag(&Kc[lds_blk(wave * 32 + l32, ks * 2 + hi)]);
            s0 = __builtin_amdgcn_mfma_f32_32x32x16_bf16(kf, qf[0][ks], s0, 0, 0, 0);
            s1 = __builtin_amdgcn_mfma_f32_32x32x16_bf16(kf, qf[1][ks], s1, 0, 0, 0);
        }

        // exp (m=0); lane holds P for 16 keys per qh: k_loc=(r&3)+8*(r>>2)+4*hi
        float p0[16], p1[16];
        float ls0 = 0.f, ls1 = 0.f;
        #pragma unroll
        for (int r = 0; r < 16; ++r) { p0[r] = __expf(s0[r]); ls0 += p0[r]; }
        #pragma unroll
        for (int r = 0; r < 16; ++r) { p1[r] = __expf(s1[r]); ls1 += p1[r]; }
        lacc0 += ls0; lacc1 += ls1;

        // PV: per key-16-slice s, build pb for both q-halves, ONE V read per
        // (s, eb) feeds both. V octet = wave*4 + s*2 + hi.
        #pragma unroll
        for (int s = 0; s < 2; ++s) {
            unsigned a0 = pk2(p0[s * 8 + 0], p0[s * 8 + 1]);
            unsigned a1 = pk2(p0[s * 8 + 2], p0[s * 8 + 3]);
            unsigned b0 = pk2(p0[s * 8 + 4], p0[s * 8 + 5]);
            unsigned b1 = pk2(p0[s * 8 + 6], p0[s * 8 + 7]);
            asm volatile("v_permlane32_swap_b32 %0, %1" : "+v"(a0), "+v"(b0));
            asm volatile("v_permlane32_swap_b32 %0, %1" : "+v"(a1), "+v"(b1));
            uint4 u0 = make_uint4(a0, a1, b0, b1);
            bf16x8 pb0 = __builtin_bit_cast(bf16x8, u0);
            unsigned c0 = pk2(p1[s * 8 + 0], p1[s * 8 + 1]);
            unsigned c1 = pk2(p1[s * 8 + 2], p1[s * 8 + 3]);
            unsigned d0 = pk2(p1[s * 8 + 4], p1[s * 8 + 5]);
            unsigned d1 = pk2(p1[s * 8 + 6], p1[s * 8 + 7]);
            asm volatile("v_permlane32_swap_b32 %0, %1" : "+v"(c0), "+v"(d0));
            asm volatile("v_permlane32_swap_b32 %0, %1" : "+v"(c1), "+v"(d1));
            uint4 u1 = make_uint4(c0, c1, d0, d1);
            bf16x8 pb1 = __builtin_bit_cast(bf16x8, u1);
            #pragma unroll
            for (int eb = 0; eb < 2; ++eb) {
                bf16x8 vf = ld_frag(
                    &Vc[lds_blkV(eb * 32 + l32, wave * 4 + s * 2 + hi)]);
                oacc[0][eb] = __builtin_amdgcn_mfma_f32_32x32x16_bf16(
                    vf, pb0, oacc[0][eb], 0, 0, 0);
                oacc[1][eb] = __builtin_amdgcn_mfma_f32_32x32x16_bf16(
                    vf, pb1, oacc[1][eb], 0, 0, 0);
            }
        }

        __syncthreads();   // drains vmcnt (tile j+1 committed) + lgkm; flips bufs
    }

    // ---- epilogue: 4-way combine through LDS overlay, normalize, store ----
    lacc0 += __shfl_xor(lacc0, 32);            // combine hi-halves: l over 32 keys
    lacc1 += __shfl_xor(lacc1, 32);
    // write partials: Op[wave][q][e] (q-major, e padded to 66)
    #pragma unroll
    for (int qh = 0; qh < 2; ++qh)
        #pragma unroll
        for (int eb = 0; eb < 2; ++eb)
            #pragma unroll
            for (int rg = 0; rg < 4; ++rg) {
                f32x4 v = {oacc[qh][eb][rg * 4 + 0], oacc[qh][eb][rg * 4 + 1],
                           oacc[qh][eb][rg * 4 + 2], oacc[qh][eb][rg * 4 + 3]};
                *reinterpret_cast<f32x4*>(
                    &Op[wave * 4224 + (qh * 32 + l32) * 66 +
                        eb * 32 + rg * 8 + hi * 4]) = v;
            }
    if (hi == 0) {
        Ls[wave * 64 + l32]      = lacc0;
        Ls[wave * 64 + 32 + l32] = lacc1;
    }
    __syncthreads();
    {
        const int q  = wave * 16 + (lane >> 2);   // wave owns a 16-q slice
        const int ec = (lane & 3) * 16;
        const float li = 1.0f / (Ls[q] + Ls[64 + q] + Ls[128 + q] + Ls[192 + q]);
        unsigned short* op =
            aob + (size_t)(b * NSEQ + n0 + q) * D_ + h * 64 + ec;
        #pragma unroll
        for (int i = 0; i < 4; ++i) {
            const int e = ec + i * 4;
            f32x4 a = *reinterpret_cast<const f32x4*>(&Op[q * 66 + e]);
            f32x4 a1 = *reinterpret_cast<const f32x4*>(&Op[4224 + q * 66 + e]);
            f32x4 a2 = *reinterpret_cast<const f32x4*>(&Op[8448 + q * 66 + e]);
            f32x4 a3 = *reinterpret_cast<const f32x4*>(&Op[12672 + q * 66 + e]);
            a = (a + a1) + (a2 + a3);
            ushort4 st = make_ushort4(f2b(a.x * li), f2b(a.y * li),
                                      f2b(a.z * li), f2b(a.w * li));
            *reinterpret_cast<ushort4*>(op + i * 4) = st;
        }
    }
    #undef ATTN_STAGE
}

// ---------------------------------------------------------------------------
// Output NT-GEMM: Out[m][o] = sum_d aob[m][d] * Wout[o][d]. 8192x512x512.
// Interleaved-2 LDS layout; fp32 direct-store epilogue. (FROZEN control)
// ---------------------------------------------------------------------------
__global__ __launch_bounds__(256, 3)
void out_gemm(const unsigned short* __restrict__ A,
              const unsigned short* __restrict__ Wo,
              float* __restrict__ Out) {
    const int m0  = blockIdx.x * 128;
    const int no0 = blockIdx.y * 64;
    const int tid = threadIdx.x;
    const int wave = tid >> 6, lane = tid & 63;
    const int quad = lane >> 4, l16 = lane & 15;

    __shared__ unsigned short Ab[2][8192];
    __shared__ unsigned short Bb[2][4096];

    const unsigned short* Ap = A + (size_t)m0 * D_;
    const unsigned short* Bp = Wo + (size_t)no0 * D_;

    int rowA[4], slA[4], rowB[2], slB[2];
    #pragma unroll
    for (int i = 0; i < 4; ++i) STAGE_SRC(wave * 32 + i * 8, lane, rowA[i], slA[i])
    #pragma unroll
    for (int i = 0; i < 2; ++i) STAGE_SRC(wave * 16 + i * 8, lane, rowB[i], slB[i])

    #define OUT_STAGE(kt, buf)                                                 \
        {   _Pragma("unroll")                                                  \
            for (int i = 0; i < 4; ++i)                                        \
                async_copy16(Ap + (size_t)rowA[i] * D_ + (kt) * 64 + slA[i] * 8, \
                             &Ab[buf][(wave * 32 + i * 8) * 64]);              \
            _Pragma("unroll")                                                  \
            for (int i = 0; i < 2; ++i)                                        \
                async_copy16(Bp + (size_t)rowB[i] * D_ + (kt) * 64 + slB[i] * 8, \
                             &Bb[buf][(wave * 16 + i * 8) * 64]);              \
        }

    OUT_STAGE(0, 0)
    __syncthreads();

    const f32x4 z = {0.f, 0.f, 0.f, 0.f};
    f32x4 acc[2][4];
    #pragma unroll
    for (int i = 0; i < 2; ++i)
        #pragma unroll
        for (int j = 0; j < 4; ++j) acc[i][j] = z;

    for (int kt = 0; kt < 8; ++kt) {
        const int cur = kt & 1;
        if (kt + 1 < 8) OUT_STAGE(kt + 1, 1 - cur)
        #pragma unroll
        for (int kk = 0; kk < 2; ++kk) {
            const int s = kk * 4 + quad;
            bf16x8 bfr[4];
            #pragma unroll
            for (int nt = 0; nt < 4; ++nt)
                bfr[nt] = ld_frag(&Bb[cur][lds_blk(nt * 16 + l16, s)]);
            #pragma unroll
            for (int mt = 0; mt < 2; ++mt) {
                bf16x8 af = ld_frag(&Ab[cur][lds_blk(wave * 32 + mt * 16 + l16, s)]);
                #pragma unroll
                for (int nt = 0; nt < 4; ++nt)
                    acc[mt][nt] = __builtin_amdgcn_mfma_f32_16x16x32_bf16(
                        af, bfr[nt], acc[mt][nt], 0, 0, 0);
            }
        }
        __syncthreads();
    }
    #pragma unroll
    for (int mt = 0; mt < 2; ++mt)
        #pragma unroll
        for (int nt = 0; nt < 4; ++nt)
            #pragma unroll
            for (int r = 0; r < 4; ++r)
                Out[(size_t)(m0 + wave * 32 + mt * 16 + quad * 4 + r) * D_ +
                    no0 + nt * 16 + l16] = acc[mt][nt][r];
    #undef OUT_STAGE
}

// ---------------------------------------------------------------------------
extern "C" void kernel_launch(void* const* d_in, const int* in_sizes, int n_in,
                              void* d_out, int out_size, void* d_ws, size_t ws_size,
                              hipStream_t stream) {
    const float* keys   = (const float*)d_in[0];
    const float* values = (const float*)d_in[1];
    const float* query  = (const float*)d_in[2];
    const float* Wk     = (const float*)d_in[3];
    const float* Wv     = (const float*)d_in[4];
    const float* Wq     = (const float*)d_in[5];
    const float* Wout   = (const float*)d_in[6];
    float* out = (float*)d_out;

    unsigned short* ws16 = (unsigned short*)d_ws;
    const size_t XN = (size_t)B_ * NSEQ * D_;      // 4,194,304
    const size_t WN = (size_t)H_ * D_ * E_;        // 262,144
    unsigned short* wkt = ws16;                    // [he][d]
    unsigned short* wvt = wkt + WN;
    unsigned short* wqt = wvt + WN;                // pre-scaled by 1/64
    unsigned short* wob = wqt + WN;
    unsigned short* qb  = wob + WN;                // [8192][512], col=h*64+e
    unsigned short* kb  = qb + XN;                 // [8192][512]
    unsigned short* vtb = kb + XN;                 // [b][h][e][n]
    unsigned short* aob = vtb + XN;                // [8192][512] head-concat
    unsigned short* qx  = aob + XN;                // bf16 query  [8192][512]
    unsigned short* kx  = qx + XN;                 // bf16 keys   [8192][512]
    unsigned short* vx  = aob;                     // bf16 values ALIASES aob:
                                                   // vx dead after proj; aob
                                                   // written only by attn (later)

    cast_w_kernel<<<dim3(1024, 4), 256, 0, stream>>>(Wk, Wv, Wq, Wout,
                                                     wkt, wvt, wqt, wob);

    xcast_kernel<<<dim3(1024, 3), 256, 0, stream>>>(query, keys, values,
                                                    qx, kx, vx);

    proj_gemm<<<dim3(64, 8, 3), 256, 0, stream>>>(
        qx, kx, vx, wqt, wkt, wvt, qb, kb, vtb);

    attn_kernel<<<dim3(1024), 256, 0, stream>>>(qb, kb, vtb, aob);

    out_gemm<<<dim3(64, 8), 256, 0, stream>>>(aob, wob, out);
}

// Round 8
// 188.050 us; speedup vs baseline: 1.0664x; 1.0664x over previous
//
#include <hip/hip_runtime.h>

// B=4, H=8, Nt=Nc=2048, D=512, E=64, scale = 1/64 folded into Wq at cast.
#define B_   4
#define H_   8
#define NSEQ 2048
#define D_   512
#define E_   64

typedef __bf16 bf16x8 __attribute__((ext_vector_type(8)));
typedef float  f32x4  __attribute__((ext_vector_type(4)));
typedef float  f32x16 __attribute__((ext_vector_type(16)));

__device__ __forceinline__ unsigned short f2b(float f) {
    __bf16 h = (__bf16)f;                     // RNE
    return __builtin_bit_cast(unsigned short, h);
}
__device__ __forceinline__ unsigned pk2(float a, float b) {
    return (unsigned)f2b(a) | ((unsigned)f2b(b) << 16);
}
__device__ __forceinline__ bf16x8 ld_frag(const unsigned short* p) {
    return *reinterpret_cast<const bf16x8*>(p);
}
// async global->LDS, 16B per lane: LDS dest = wave-uniform base + lane*16.
__device__ __forceinline__ void async_copy16(const void* g, const unsigned short* l) {
    __builtin_amdgcn_global_load_lds(
        (const __attribute__((address_space(1))) unsigned int*)g,
        (__attribute__((address_space(3))) unsigned int*)l, 16, 0, 0);
}

// ---------------------------------------------------------------------------
// Interleaved-2 LDS tile layout for 128-B rows (conflict-free b128 reads).
// 16B block (r, s) [s = 0..7] -> lr = r>>1; phys = (((r&1)<<3)|s) ^ (lr&15).
// ---------------------------------------------------------------------------
__device__ __forceinline__ int lds_blk(int r, int s) {
    int lr = r >> 1;
    return lr * 128 + (((((r & 1) << 3) | s) ^ (lr & 15)) << 3);  // ushort idx
}
#define STAGE_SRC(r0, l, row, slot)                                            \
    {   int lr_ = ((r0) >> 1) + ((l) >> 4);                                    \
        int B_x = ((l) & 15) ^ (lr_ & 15);                                     \
        row = (lr_ << 1) | (B_x >> 3);  slot = B_x & 7; }

// ---------------------------------------------------------------------------
// Cast + transpose W: [H][D][E] fp32 -> [he][d] bf16 (y=0..2); Wout (y=3).
// Wq (y=2) pre-scaled by 1/64 (exact exponent shift).
// ---------------------------------------------------------------------------
__global__ __launch_bounds__(256)
void cast_w_kernel(const float* __restrict__ Wk, const float* __restrict__ Wv,
                   const float* __restrict__ Wq, const float* __restrict__ Wo,
                   unsigned short* __restrict__ okt, unsigned short* __restrict__ ovt,
                   unsigned short* __restrict__ oqt, unsigned short* __restrict__ oo) {
    int idx = blockIdx.x * 256 + threadIdx.x;   // < 262144
    int y = blockIdx.y;
    if (y == 3) { oo[idx] = f2b(Wo[idx]); return; }
    const float* src = y == 0 ? Wk : (y == 1 ? Wv : Wq);
    unsigned short* dst = y == 0 ? okt : (y == 1 ? ovt : oqt);
    float scl = (y == 2) ? 0.015625f : 1.0f;
    int hh = idx >> 15, rem = idx & 32767, d = rem >> 6, e = rem & 63;
    dst[hh * 32768 + e * 512 + d] = f2b(src[idx] * scl);   // [(h*64+e)][d]
}

// ---------------------------------------------------------------------------
// X cast: fp32 [8192][512] -> bf16 [8192][512], y selects q/k/v.
// ---------------------------------------------------------------------------
__global__ __launch_bounds__(256)
void xcast_kernel(const float* __restrict__ q, const float* __restrict__ k,
                  const float* __restrict__ v,
                  unsigned short* __restrict__ qx, unsigned short* __restrict__ kx,
                  unsigned short* __restrict__ vx) {
    const int y = blockIdx.y;
    const float* src = y == 0 ? q : (y == 1 ? k : v);
    unsigned short* dst = y == 0 ? qx : (y == 1 ? kx : vx);
    #pragma unroll
    for (int i = 0; i < 4; ++i) {
        int e = blockIdx.x * 4096 + i * 1024 + threadIdx.x * 4;
        float4 f = *reinterpret_cast<const float4*>(src + e);
        *reinterpret_cast<ushort4*>(dst + e) =
            make_ushort4(f2b(f.x), f2b(f.y), f2b(f.z), f2b(f.w));
    }
}

// ---------------------------------------------------------------------------
// Projection NT-GEMM (pure bf16): C[m][he] = sum_d X[m][d]*Wt[he][d].
// 8192x512x512, which: 0=Q 1=K 2=V.
// 128x128 tile, BK=64, 4 waves in 2x2 quadrants, acc 4x4 frags/wave:
// per kk 8 ds_read_b128 feed 16 MFMAs (2x the 128x64 ratio), B-traffic
// per output halves. Interleaved-2 LDS, global_load_lds staging, one
// barrier/K-iter. LDS 64 KB -> 2 blocks/CU. Grid (64, 4, 3).
// ---------------------------------------------------------------------------
__global__ __launch_bounds__(256, 2)
void proj_gemm(const unsigned short* __restrict__ qx,
               const unsigned short* __restrict__ kx,
               const unsigned short* __restrict__ vx,
               const unsigned short* __restrict__ wqt,
               const unsigned short* __restrict__ wkt,
               const unsigned short* __restrict__ wvt,
               unsigned short* __restrict__ qb, unsigned short* __restrict__ kb,
               unsigned short* __restrict__ vtb) {
    const int m0  = blockIdx.x * 128;
    const int no0 = blockIdx.y * 128;
    const int which = blockIdx.z;
    const int tid = threadIdx.x;
    const int wave = tid >> 6, lane = tid & 63;
    const int quad = lane >> 4, l16 = lane & 15;
    const int wr = wave >> 1, wc = wave & 1;

    const unsigned short* X = which == 0 ? qx : (which == 1 ? kx : vx);
    const unsigned short* W = which == 0 ? wqt : (which == 1 ? wkt : wvt);

    __shared__ unsigned short SM[32768];     // 64 KB
    unsigned short* Ab = SM;                 // [2][128 r][64 d] interleaved-2
    unsigned short* Bb = SM + 16384;         // [2][128 r][64 d] interleaved-2

    const unsigned short* Xp = X + (size_t)m0 * D_;
    const unsigned short* Wp = W + (size_t)no0 * D_;

    // per-lane staging source (loop-invariant): 4 slabs of 8 rows per wave,
    // same row set for A and B (both tiles are 128 rows).
    int rowS[4], slS[4];
    #pragma unroll
    for (int i = 0; i < 4; ++i) STAGE_SRC(wave * 32 + i * 8, lane, rowS[i], slS[i])

    #define PROJ_STAGE(kt, buf)                                                \
        {   _Pragma("unroll")                                                  \
            for (int i = 0; i < 4; ++i)                                        \
                async_copy16(Xp + (size_t)rowS[i] * D_ + (kt) * 64 + slS[i] * 8, \
                             Ab + (buf) * 8192 + (wave * 32 + i * 8) * 64);    \
            _Pragma("unroll")                                                  \
            for (int i = 0; i < 4; ++i)                                        \
                async_copy16(Wp + (size_t)rowS[i] * D_ + (kt) * 64 + slS[i] * 8, \
                             Bb + (buf) * 8192 + (wave * 32 + i * 8) * 64);    \
        }

    PROJ_STAGE(0, 0)
    __syncthreads();                          // vmcnt drain: tile 0 resident

    const f32x4 z = {0.f, 0.f, 0.f, 0.f};
    f32x4 acc[4][4];
    #pragma unroll
    for (int i = 0; i < 4; ++i)
        #pragma unroll
        for (int j = 0; j < 4; ++j) acc[i][j] = z;

    for (int kt = 0; kt < 8; ++kt) {
        const int cur = kt & 1;
        if (kt + 1 < 8) PROJ_STAGE(kt + 1, 1 - cur)   // in flight over compute
        #pragma unroll
        for (int kk = 0; kk < 2; ++kk) {
            const int s = kk * 4 + quad;      // 16B slot of this k-octet
            bf16x8 bfr[4];
            #pragma unroll
            for (int nt = 0; nt < 4; ++nt)
                bfr[nt] = ld_frag(&Bb[cur * 8192 +
                                      lds_blk(wc * 64 + nt * 16 + l16, s)]);
            #pragma unroll
            for (int mt = 0; mt < 4; ++mt) {
                bf16x8 af = ld_frag(&Ab[cur * 8192 +
                                        lds_blk(wr * 64 + mt * 16 + l16, s)]);
                #pragma unroll
                for (int nt = 0; nt < 4; ++nt)
                    acc[mt][nt] = __builtin_amdgcn_mfma_f32_16x16x32_bf16(
                        af, bfr[nt], acc[mt][nt], 0, 0, 0);
            }
        }
        __syncthreads();                      // drains vmcnt (tile kt+1) + lgkm
    }

    // epilogue: overlay restage on SM (64 KB available, tiles dead)
    if (which != 2) {
        unsigned short (*Os)[136] = reinterpret_cast<unsigned short(*)[136]>(SM);
        #pragma unroll
        for (int mt = 0; mt < 4; ++mt)
            #pragma unroll
            for (int nt = 0; nt < 4; ++nt)
                #pragma unroll
                for (int r = 0; r < 4; ++r)
                    Os[wr * 64 + mt * 16 + quad * 4 + r][wc * 64 + nt * 16 + l16] =
                        f2b(acc[mt][nt][r]);
        __syncthreads();
        unsigned short* Y = (which == 0 ? qb : kb);
        #pragma unroll
        for (int i = 0; i < 8; ++i) {           // 128 rows x 16 uint4
            int idx = tid + i * 256;
            int row = idx >> 4, seg = idx & 15;
            *reinterpret_cast<uint4*>(Y + (size_t)(m0 + row) * D_ + no0 + seg * 8) =
                *reinterpret_cast<const uint4*>(&Os[row][seg * 8]);
        }
    } else {
        unsigned short (*Ot)[138] = reinterpret_cast<unsigned short(*)[138]>(SM);
        #pragma unroll
        for (int mt = 0; mt < 4; ++mt)
            #pragma unroll
            for (int nt = 0; nt < 4; ++nt) {
                ushort4 o = make_ushort4(f2b(acc[mt][nt][0]), f2b(acc[mt][nt][1]),
                                         f2b(acc[mt][nt][2]), f2b(acc[mt][nt][3]));
                *reinterpret_cast<ushort4*>(
                    &Ot[wc * 64 + nt * 16 + l16][wr * 64 + mt * 16 + quad * 4]) = o;
            }
        __syncthreads();
        const int b = m0 >> 11, nloc = m0 & 2047;
        #pragma unroll
        for (int i = 0; i < 8; ++i) {           // 128 he-rows x 16 uint4
            int idx = tid + i * 256;
            int lhe = idx >> 4, seg = idx & 15;
            int ghe = no0 + lhe;                 // h = ghe>>6, e = ghe&63
            *reinterpret_cast<uint4*>(
                vtb + ((size_t)(b * H_ + (ghe >> 6)) * E_ + (ghe & 63)) * NSEQ +
                nloc + seg * 8) =
                *reinterpret_cast<const uint4*>(&Ot[lhe][seg * 8]);
        }
    }
    #undef PROJ_STAGE
}

// ---------------------------------------------------------------------------
// Flash attention (REVERTED to the round-6 best: 59.2 us, 32 KB LDS,
// 4 blocks/CU). 32x32x16 MFMA, in-register P (permlane), interleaved-2
// conflict-free LDS. wk = wave>>1 (key half), wq = wave&1 (q half).
// ---------------------------------------------------------------------------
__global__ __launch_bounds__(256, 3)
void attn_kernel(const unsigned short* __restrict__ qbp,
                 const unsigned short* __restrict__ kbp,
                 const unsigned short* __restrict__ vtbp,
                 unsigned short* __restrict__ aob) {
    const int L = blockIdx.x;
    const int bh = L & 31, qt = L >> 5;      // L%8 pattern -> XCD K/V affinity
    const int b = bh >> 3, h = bh & 7;
    const int n0 = qt * 64;
    const int tid = threadIdx.x;
    const int wave = tid >> 6, lane = tid & 63;
    const int wk = wave >> 1, wq = wave & 1;
    const int l32 = lane & 31, hi = lane >> 5;

    __shared__ unsigned short Ks[2][4096];   // 16 KiB (dbuf K, 64 rows)
    __shared__ unsigned short Vs[2][4096];   // 16 KiB (dbuf V^T, 64 e-rows)

    const unsigned short* kbase = kbp + (size_t)(b * NSEQ) * D_ + h * 64;
    const unsigned short* vbase = vtbp + (size_t)(b * H_ + h) * E_ * NSEQ;

    int rowS[2], slS[2];
    #pragma unroll
    for (int i = 0; i < 2; ++i) STAGE_SRC(wave * 16 + i * 8, lane, rowS[i], slS[i])

    // Q B-frags (32x32x16 B layout: lane&31 = q col, k-octet = hi):
    bf16x8 qf[4];
    #pragma unroll
    for (int ks = 0; ks < 4; ++ks)
        qf[ks] = ld_frag(qbp + (size_t)(b * NSEQ + n0 + wq * 32 + l32) * D_ +
                         h * 64 + ks * 16 + hi * 8);

    #define ATTN_STAGE(j, buf)                                                 \
        {   _Pragma("unroll")                                                  \
            for (int i = 0; i < 2; ++i) {                                      \
                async_copy16(                                                  \
                    kbase + (size_t)((j) * 64 + rowS[i]) * D_ + slS[i] * 8,    \
                    &Ks[buf][wave * 1024 + i * 512]);                          \
                async_copy16(                                                  \
                    vbase + (size_t)rowS[i] * NSEQ + (j) * 64 + slS[i] * 8,    \
                    &Vs[buf][wave * 1024 + i * 512]);                          \
            } }

    ATTN_STAGE(0, 0)
    __syncthreads();                            // vmcnt drain: tile 0 resident

    f32x16 oacc[2] = {};                        // O^T[eb*32 + crow][q], own keys
    float lacc = 0.f;

    for (int j = 0; j < NSEQ / 64; ++j) {
        const int cur = j & 1;
        if (j + 1 < NSEQ / 64) ATTN_STAGE(j + 1, 1 - cur)   // in flight over compute

        const unsigned short* Kc = Ks[cur];
        const unsigned short* Vc = Vs[cur];

        // S-block = mfma(K, Q): A = K[key = wk*32 + l32][k-octet ks*2 + hi]
        f32x16 sacc = {};
        #pragma unroll
        for (int ks = 0; ks < 4; ++ks) {
            bf16x8 kf = ld_frag(&Kc[lds_blk(wk * 32 + l32, ks * 2 + hi)]);
            sacc = __builtin_amdgcn_mfma_f32_32x32x16_bf16(kf, qf[ks], sacc, 0, 0, 0);
        }

        // exp (m=0); lane holds P for 16 keys: k_local = (r&3)+8*(r>>2)+4*hi
        float p[16];
        #pragma unroll
        for (int r = 0; r < 16; ++r) p[r] = __expf(sacc[r]);
        lacc += ((p[0] + p[1]) + (p[2] + p[3])) + ((p[4] + p[5]) + (p[6] + p[7])) +
                (((p[8] + p[9]) + (p[10] + p[11])) + ((p[12] + p[13]) + (p[14] + p[15])));

        // Build PV B-frags in-register: pack bf16 pairs, then swap lane-halves.
        #pragma unroll
        for (int s = 0; s < 2; ++s) {
            unsigned x0 = pk2(p[s * 8 + 0], p[s * 8 + 1]);
            unsigned x1 = pk2(p[s * 8 + 2], p[s * 8 + 3]);
            unsigned y0 = pk2(p[s * 8 + 4], p[s * 8 + 5]);
            unsigned y1 = pk2(p[s * 8 + 6], p[s * 8 + 7]);
            asm volatile("v_permlane32_swap_b32 %0, %1" : "+v"(x0), "+v"(y0));
            asm volatile("v_permlane32_swap_b32 %0, %1" : "+v"(x1), "+v"(y1));
            uint4 u = make_uint4(x0, x1, y0, y1);
            bf16x8 pb = __builtin_bit_cast(bf16x8, u);
            // O^T += V^T·P : A = V^T[e = eb*32 + l32][k-octet wk*4 + s*2 + hi]
            #pragma unroll
            for (int eb = 0; eb < 2; ++eb) {
                bf16x8 vf = ld_frag(&Vc[lds_blk(eb * 32 + l32, wk * 4 + s * 2 + hi)]);
                oacc[eb] = __builtin_amdgcn_mfma_f32_32x32x16_bf16(
                    vf, pb, oacc[eb], 0, 0, 0);
            }
        }

        __syncthreads();   // drains vmcnt (tile j+1 committed) + lgkm; flips buffers
    }

    // ---- epilogue: combine wk pairs through LDS (Ks/Vs dead), normalize ----
    lacc += __shfl_xor(lacc, 32);              // wave partial l(q), q = l32
    float* Of = reinterpret_cast<float*>(&Ks[0][0]);   // [wq][32 q][64 e] = 16 KB
    float* Lf = reinterpret_cast<float*>(&Vs[0][0]);   // [wq][32 q]
    if (wk == 0) {
        #pragma unroll
        for (int eb = 0; eb < 2; ++eb)
            #pragma unroll
            for (int rg = 0; rg < 4; ++rg) {
                f32x4 v = {oacc[eb][rg * 4 + 0], oacc[eb][rg * 4 + 1],
                           oacc[eb][rg * 4 + 2], oacc[eb][rg * 4 + 3]};
                *reinterpret_cast<f32x4*>(
                    &Of[(wq * 32 + l32) * 64 + eb * 32 + rg * 8 + hi * 4]) = v;
            }
        if (hi == 0) Lf[wq * 32 + l32] = lacc;
    }
    __syncthreads();
    if (wk == 1) {
        const float li = 1.0f / (lacc + Lf[wq * 32 + l32]);
        unsigned short* op =
            aob + (size_t)(b * NSEQ + n0 + wq * 32 + l32) * D_ + h * 64;
        #pragma unroll
        for (int eb = 0; eb < 2; ++eb)
            #pragma unroll
            for (int rg = 0; rg < 4; ++rg) {
                const f32x4 o = *reinterpret_cast<const f32x4*>(
                    &Of[(wq * 32 + l32) * 64 + eb * 32 + rg * 8 + hi * 4]);
                ushort4 st = make_ushort4(f2b((oacc[eb][rg * 4 + 0] + o.x) * li),
                                          f2b((oacc[eb][rg * 4 + 1] + o.y) * li),
                                          f2b((oacc[eb][rg * 4 + 2] + o.z) * li),
                                          f2b((oacc[eb][rg * 4 + 3] + o.w) * li));
                *reinterpret_cast<ushort4*>(op + eb * 32 + rg * 8 + hi * 4) = st;
            }
    }
    #undef ATTN_STAGE
}

// ---------------------------------------------------------------------------
// Output NT-GEMM: Out[m][o] = sum_d aob[m][d] * Wout[o][d]. 8192x512x512.
// 128x128 tile, same structure as proj_gemm; fp32 direct-store epilogue.
// Grid (64, 4) = 256 blocks.
// ---------------------------------------------------------------------------
__global__ __launch_bounds__(256, 2)
void out_gemm(const unsigned short* __restrict__ A,
              const unsigned short* __restrict__ Wo,
              float* __restrict__ Out) {
    const int m0  = blockIdx.x * 128;
    const int no0 = blockIdx.y * 128;
    const int tid = threadIdx.x;
    const int wave = tid >> 6, lane = tid & 63;
    const int quad = lane >> 4, l16 = lane & 15;
    const int wr = wave >> 1, wc = wave & 1;

    __shared__ unsigned short SM[32768];     // 64 KB
    unsigned short* Ab = SM;
    unsigned short* Bb = SM + 16384;

    const unsigned short* Ap = A + (size_t)m0 * D_;
    const unsigned short* Bp = Wo + (size_t)no0 * D_;

    int rowS[4], slS[4];
    #pragma unroll
    for (int i = 0; i < 4; ++i) STAGE_SRC(wave * 32 + i * 8, lane, rowS[i], slS[i])

    #define OUT_STAGE(kt, buf)                                                 \
        {   _Pragma("unroll")                                                  \
            for (int i = 0; i < 4; ++i)                                        \
                async_copy16(Ap + (size_t)rowS[i] * D_ + (kt) * 64 + slS[i] * 8, \
                             Ab + (buf) * 8192 + (wave * 32 + i * 8) * 64);    \
            _Pragma("unroll")                                                  \
            for (int i = 0; i < 4; ++i)                                        \
                async_copy16(Bp + (size_t)rowS[i] * D_ + (kt) * 64 + slS[i] * 8, \
                             Bb + (buf) * 8192 + (wave * 32 + i * 8) * 64);    \
        }

    OUT_STAGE(0, 0)
    __syncthreads();

    const f32x4 z = {0.f, 0.f, 0.f, 0.f};
    f32x4 acc[4][4];
    #pragma unroll
    for (int i = 0; i < 4; ++i)
        #pragma unroll
        for (int j = 0; j < 4; ++j) acc[i][j] = z;

    for (int kt = 0; kt < 8; ++kt) {
        const int cur = kt & 1;
        if (kt + 1 < 8) OUT_STAGE(kt + 1, 1 - cur)
        #pragma unroll
        for (int kk = 0; kk < 2; ++kk) {
            const int s = kk * 4 + quad;
            bf16x8 bfr[4];
            #pragma unroll
            for (int nt = 0; nt < 4; ++nt)
                bfr[nt] = ld_frag(&Bb[cur * 8192 +
                                      lds_blk(wc * 64 + nt * 16 + l16, s)]);
            #pragma unroll
            for (int mt = 0; mt < 4; ++mt) {
                bf16x8 af = ld_frag(&Ab[cur * 8192 +
                                        lds_blk(wr * 64 + mt * 16 + l16, s)]);
                #pragma unroll
                for (int nt = 0; nt < 4; ++nt)
                    acc[mt][nt] = __builtin_amdgcn_mfma_f32_16x16x32_bf16(
                        af, bfr[nt], acc[mt][nt], 0, 0, 0);
            }
        }
        __syncthreads();
    }
    #pragma unroll
    for (int mt = 0; mt < 4; ++mt)
        #pragma unroll
        for (int nt = 0; nt < 4; ++nt)
            #pragma unroll
            for (int r = 0; r < 4; ++r)
                Out[(size_t)(m0 + wr * 64 + mt * 16 + quad * 4 + r) * D_ +
                    no0 + wc * 64 + nt * 16 + l16] = acc[mt][nt][r];
    #undef OUT_STAGE
}

// ---------------------------------------------------------------------------
extern "C" void kernel_launch(void* const* d_in, const int* in_sizes, int n_in,
                              void* d_out, int out_size, void* d_ws, size_t ws_size,
                              hipStream_t stream) {
    const float* keys   = (const float*)d_in[0];
    const float* values = (const float*)d_in[1];
    const float* query  = (const float*)d_in[2];
    const float* Wk     = (const float*)d_in[3];
    const float* Wv     = (const float*)d_in[4];
    const float* Wq     = (const float*)d_in[5];
    const float* Wout   = (const float*)d_in[6];
    float* out = (float*)d_out;

    unsigned short* ws16 = (unsigned short*)d_ws;
    const size_t XN = (size_t)B_ * NSEQ * D_;      // 4,194,304
    const size_t WN = (size_t)H_ * D_ * E_;        // 262,144
    unsigned short* wkt = ws16;                    // [he][d]
    unsigned short* wvt = wkt + WN;
    unsigned short* wqt = wvt + WN;                // pre-scaled by 1/64
    unsigned short* wob = wqt + WN;
    unsigned short* qb  = wob + WN;                // [8192][512], col=h*64+e
    unsigned short* kb  = qb + XN;                 // [8192][512]
    unsigned short* vtb = kb + XN;                 // [b][h][e][n]
    unsigned short* aob = vtb + XN;                // [8192][512] head-concat
    unsigned short* qx  = aob + XN;                // bf16 query  [8192][512]
    unsigned short* kx  = qx + XN;                 // bf16 keys   [8192][512]
    unsigned short* vx  = aob;                     // bf16 values ALIASES aob:
                                                   // vx dead after proj; aob
                                                   // written only by attn (later)

    cast_w_kernel<<<dim3(1024, 4), 256, 0, stream>>>(Wk, Wv, Wq, Wout,
                                                     wkt, wvt, wqt, wob);

    xcast_kernel<<<dim3(1024, 3), 256, 0, stream>>>(query, keys, values,
                                                    qx, kx, vx);

    proj_gemm<<<dim3(64, 4, 3), 256, 0, stream>>>(
        qx, kx, vx, wqt, wkt, wvt, qb, kb, vtb);

    attn_kernel<<<dim3(1024), 256, 0, stream>>>(qb, kb, vtb, aob);

    out_gemm<<<dim3(64, 4), 256, 0, stream>>>(aob, wob, out);
}

// Round 9
// 187.363 us; speedup vs baseline: 1.0703x; 1.0037x over previous
//
#include <hip/hip_runtime.h>

// B=4, H=8, Nt=Nc=2048, D=512, E=64, scale = 1/64 folded into Wq at cast.
#define B_   4
#define H_   8
#define NSEQ 2048
#define D_   512
#define E_   64

typedef __bf16 bf16x8 __attribute__((ext_vector_type(8)));
typedef float  f32x4  __attribute__((ext_vector_type(4)));
typedef float  f32x16 __attribute__((ext_vector_type(16)));

__device__ __forceinline__ unsigned short f2b(float f) {
    __bf16 h = (__bf16)f;                     // RNE
    return __builtin_bit_cast(unsigned short, h);
}
__device__ __forceinline__ unsigned pk2(float a, float b) {
    return (unsigned)f2b(a) | ((unsigned)f2b(b) << 16);
}
__device__ __forceinline__ bf16x8 ld_frag(const unsigned short* p) {
    return *reinterpret_cast<const bf16x8*>(p);
}
// async global->LDS, 16B per lane: LDS dest = wave-uniform base + lane*16.
__device__ __forceinline__ void async_copy16(const void* g, const unsigned short* l) {
    __builtin_amdgcn_global_load_lds(
        (const __attribute__((address_space(1))) unsigned int*)g,
        (__attribute__((address_space(3))) unsigned int*)l, 16, 0, 0);
}

// ---------------------------------------------------------------------------
// Interleaved-2 layout for 128-B rows (8 slots): attn K/V tiles (verified).
// ---------------------------------------------------------------------------
__device__ __forceinline__ int lds_blk(int r, int s) {
    int lr = r >> 1;
    return lr * 128 + (((((r & 1) << 3) | s) ^ (lr & 15)) << 3);  // ushort idx
}
#define STAGE_SRC(r0, l, row, slot)                                            \
    {   int lr_ = ((r0) >> 1) + ((l) >> 4);                                    \
        int B_x = ((l) & 15) ^ (lr_ & 15);                                     \
        row = (lr_ << 1) | (B_x >> 3);  slot = B_x & 7; }

// ---------------------------------------------------------------------------
// Interleaved-4 layout for 64-B rows (4 slots) — BK=32 GEMM tiles.
// Block (r, s∈0..3): lr = r>>2; phys16 = (((r&3)<<2)|s) ^ (lr&15).
// Bank count per wave frag-read (rows base..base+15 x slots quad): every
// bank receives exactly 8 word-requests = the 1 KB/wave floor (conflict-free).
// Staging inverse (16 rows per glds instruction) composes to identity.
// ---------------------------------------------------------------------------
__device__ __forceinline__ int lds_blk32(int r, int s) {
    int lr = r >> 2;
    return lr * 128 + (((((r & 3) << 2) | s) ^ (lr & 15)) << 3);  // ushort idx
}
#define STAGE_SRC32(r0, l, row, slot)                                          \
    {   int lr_ = ((r0) >> 2) + ((l) >> 4);                                    \
        int B_x = ((l) & 15) ^ (lr_ & 15);                                     \
        row = (lr_ << 2) | (B_x >> 2);  slot = B_x & 3; }

// ---------------------------------------------------------------------------
// Fused prep: y=0..2 -> X cast fp32->bf16 (q/k/v); y=3 -> all W casts
// (Wk/Wv/Wq transposed to [he][d], Wq pre-scaled 1/64; Wout straight).
// One launch replaces cast_w + xcast.
// ---------------------------------------------------------------------------
__global__ __launch_bounds__(256)
void prep_kernel(const float* __restrict__ q, const float* __restrict__ k,
                 const float* __restrict__ v,
                 const float* __restrict__ Wk, const float* __restrict__ Wv,
                 const float* __restrict__ Wq, const float* __restrict__ Wo,
                 unsigned short* __restrict__ qx, unsigned short* __restrict__ kx,
                 unsigned short* __restrict__ vx,
                 unsigned short* __restrict__ okt, unsigned short* __restrict__ ovt,
                 unsigned short* __restrict__ oqt, unsigned short* __restrict__ oo) {
    const int y = blockIdx.y;
    if (y == 3) {
        int idx = blockIdx.x * 256 + threadIdx.x;   // < 262144
        int hh = idx >> 15, rem = idx & 32767, d = rem >> 6, e = rem & 63;
        int t = hh * 32768 + e * 512 + d;            // [(h*64+e)][d]
        okt[t] = f2b(Wk[idx]);
        ovt[t] = f2b(Wv[idx]);
        oqt[t] = f2b(Wq[idx] * 0.015625f);
        oo[idx] = f2b(Wo[idx]);
        return;
    }
    const float* src = y == 0 ? q : (y == 1 ? k : v);
    unsigned short* dst = y == 0 ? qx : (y == 1 ? kx : vx);
    #pragma unroll
    for (int i = 0; i < 4; ++i) {
        int e = blockIdx.x * 4096 + i * 1024 + threadIdx.x * 4;
        float4 f = *reinterpret_cast<const float4*>(src + e);
        *reinterpret_cast<ushort4*>(dst + e) =
            make_ushort4(f2b(f.x), f2b(f.y), f2b(f.z), f2b(f.w));
    }
}

// ---------------------------------------------------------------------------
// Projection NT-GEMM (pure bf16): C[m][he] = sum_d X[m][d]*Wt[he][d].
// 8192x512x512, which: 0=Q 1=K 2=V.
// 128x128 tile, BK=32, interleaved-4 LDS (32 KB) -> 3 blocks/CU; grid
// 768 = 256 CU x 3 ALL-RESIDENT (single dispatch round, zero tail),
// 12 waves/CU. 16 K-iters; per iter 8 b128 frag reads -> 16 MFMAs.
// Accumulation order identical to BK=64 version (bit-identical output).
// ---------------------------------------------------------------------------
__global__ __launch_bounds__(256, 3)
void proj_gemm(const unsigned short* __restrict__ qx,
               const unsigned short* __restrict__ kx,
               const unsigned short* __restrict__ vx,
               const unsigned short* __restrict__ wqt,
               const unsigned short* __restrict__ wkt,
               const unsigned short* __restrict__ wvt,
               unsigned short* __restrict__ qb, unsigned short* __restrict__ kb,
               unsigned short* __restrict__ vtb) {
    const int m0  = blockIdx.x * 128;
    const int no0 = blockIdx.y * 128;
    const int which = blockIdx.z;
    const int tid = threadIdx.x;
    const int wave = tid >> 6, lane = tid & 63;
    const int quad = lane >> 4, l16 = lane & 15;
    const int wr = wave >> 1, wc = wave & 1;

    const unsigned short* X = which == 0 ? qx : (which == 1 ? kx : vx);
    const unsigned short* W = which == 0 ? wqt : (which == 1 ? wkt : wvt);

    __shared__ unsigned short SM[16384];     // 32 KB
    unsigned short* Ab = SM;                 // [2][128 r][32 d] interleaved-4
    unsigned short* Bb = SM + 8192;          // [2][128 r][32 d] interleaved-4

    const unsigned short* Xp = X + (size_t)m0 * D_;
    const unsigned short* Wp = W + (size_t)no0 * D_;

    // per-lane staging source (loop-invariant): 2 slabs of 16 rows per wave
    int rowS[2], slS[2];
    #pragma unroll
    for (int i = 0; i < 2; ++i) STAGE_SRC32(wave * 32 + i * 16, lane, rowS[i], slS[i])

    #define PROJ_STAGE(kt, buf)                                                \
        {   _Pragma("unroll")                                                  \
            for (int i = 0; i < 2; ++i)                                        \
                async_copy16(Xp + (size_t)rowS[i] * D_ + (kt) * 32 + slS[i] * 8, \
                             Ab + (buf) * 4096 + (wave * 32 + i * 16) * 32);   \
            _Pragma("unroll")                                                  \
            for (int i = 0; i < 2; ++i)                                        \
                async_copy16(Wp + (size_t)rowS[i] * D_ + (kt) * 32 + slS[i] * 8, \
                             Bb + (buf) * 4096 + (wave * 32 + i * 16) * 32);   \
        }

    PROJ_STAGE(0, 0)
    __syncthreads();                          // vmcnt drain: tile 0 resident

    const f32x4 z = {0.f, 0.f, 0.f, 0.f};
    f32x4 acc[4][4];
    #pragma unroll
    for (int i = 0; i < 4; ++i)
        #pragma unroll
        for (int j = 0; j < 4; ++j) acc[i][j] = z;

    for (int kt = 0; kt < 16; ++kt) {
        const int cur = kt & 1;
        if (kt + 1 < 16) PROJ_STAGE(kt + 1, 1 - cur)  // in flight over compute
        bf16x8 bfr[4];
        #pragma unroll
        for (int nt = 0; nt < 4; ++nt)
            bfr[nt] = ld_frag(&Bb[cur * 4096 +
                                  lds_blk32(wc * 64 + nt * 16 + l16, quad)]);
        #pragma unroll
        for (int mt = 0; mt < 4; ++mt) {
            bf16x8 af = ld_frag(&Ab[cur * 4096 +
                                    lds_blk32(wr * 64 + mt * 16 + l16, quad)]);
            #pragma unroll
            for (int nt = 0; nt < 4; ++nt)
                acc[mt][nt] = __builtin_amdgcn_mfma_f32_16x16x32_bf16(
                    af, bfr[nt], acc[mt][nt], 0, 0, 0);
        }
        __syncthreads();                      // drains vmcnt (tile kt+1) + lgkm
    }

    // epilogue: two-chunk restage through the 32 KB SM (vectorized stores)
    if (which != 2) {
        unsigned short* Y = (which == 0 ? qb : kb);
        unsigned short (*Os)[136] = reinterpret_cast<unsigned short(*)[136]>(SM);
        #pragma unroll
        for (int h = 0; h < 2; ++h) {          // chunk = m-rows [h*64, h*64+64)
            if (wr == h) {
                #pragma unroll
                for (int mt = 0; mt < 4; ++mt)
                    #pragma unroll
                    for (int nt = 0; nt < 4; ++nt)
                        #pragma unroll
                        for (int r = 0; r < 4; ++r)
                            Os[mt * 16 + quad * 4 + r][wc * 64 + nt * 16 + l16] =
                                f2b(acc[mt][nt][r]);
            }
            __syncthreads();
            #pragma unroll
            for (int i = 0; i < 4; ++i) {      // 64 rows x 16 uint4
                int idx = tid + i * 256;
                int row = idx >> 4, seg = idx & 15;
                *reinterpret_cast<uint4*>(
                    Y + (size_t)(m0 + h * 64 + row) * D_ + no0 + seg * 8) =
                    *reinterpret_cast<const uint4*>(&Os[row][seg * 8]);
            }
            if (h == 0) __syncthreads();
        }
    } else {
        unsigned short (*Ot)[144] = reinterpret_cast<unsigned short(*)[144]>(SM);
        const int b = m0 >> 11, nloc = m0 & 2047;
        #pragma unroll
        for (int h = 0; h < 2; ++h) {          // chunk = he-rows [h*64, h*64+64)
            if (wc == h) {
                #pragma unroll
                for (int mt = 0; mt < 4; ++mt)
                    #pragma unroll
                    for (int nt = 0; nt < 4; ++nt) {
                        ushort4 o = make_ushort4(
                            f2b(acc[mt][nt][0]), f2b(acc[mt][nt][1]),
                            f2b(acc[mt][nt][2]), f2b(acc[mt][nt][3]));
                        *reinterpret_cast<ushort4*>(
                            &Ot[nt * 16 + l16][wr * 64 + mt * 16 + quad * 4]) = o;
                    }
            }
            __syncthreads();
            #pragma unroll
            for (int i = 0; i < 4; ++i) {      // 64 he-rows x 16 uint4
                int idx = tid + i * 256;
                int lhe = idx >> 4, seg = idx & 15;
                int ghe = no0 + h * 64 + lhe;  // h = ghe>>6, e = ghe&63
                *reinterpret_cast<uint4*>(
                    vtb + ((size_t)(b * H_ + (ghe >> 6)) * E_ + (ghe & 63)) * NSEQ +
                    nloc + seg * 8) =
                    *reinterpret_cast<const uint4*>(&Ot[lhe][seg * 8]);
            }
            if (h == 0) __syncthreads();
        }
    }
    #undef PROJ_STAGE
}

// ---------------------------------------------------------------------------
// Flash attention (round-6 best, FROZEN: 59.0 us). 32x32x16 MFMA,
// in-register P (permlane), interleaved-2 conflict-free LDS, 32 KB.
// ---------------------------------------------------------------------------
__global__ __launch_bounds__(256, 3)
void attn_kernel(const unsigned short* __restrict__ qbp,
                 const unsigned short* __restrict__ kbp,
                 const unsigned short* __restrict__ vtbp,
                 unsigned short* __restrict__ aob) {
    const int L = blockIdx.x;
    const int bh = L & 31, qt = L >> 5;      // L%8 pattern -> XCD K/V affinity
    const int b = bh >> 3, h = bh & 7;
    const int n0 = qt * 64;
    const int tid = threadIdx.x;
    const int wave = tid >> 6, lane = tid & 63;
    const int wk = wave >> 1, wq = wave & 1;
    const int l32 = lane & 31, hi = lane >> 5;

    __shared__ unsigned short Ks[2][4096];   // 16 KiB (dbuf K, 64 rows)
    __shared__ unsigned short Vs[2][4096];   // 16 KiB (dbuf V^T, 64 e-rows)

    const unsigned short* kbase = kbp + (size_t)(b * NSEQ) * D_ + h * 64;
    const unsigned short* vbase = vtbp + (size_t)(b * H_ + h) * E_ * NSEQ;

    int rowS[2], slS[2];
    #pragma unroll
    for (int i = 0; i < 2; ++i) STAGE_SRC(wave * 16 + i * 8, lane, rowS[i], slS[i])

    // Q B-frags (32x32x16 B layout: lane&31 = q col, k-octet = hi):
    bf16x8 qf[4];
    #pragma unroll
    for (int ks = 0; ks < 4; ++ks)
        qf[ks] = ld_frag(qbp + (size_t)(b * NSEQ + n0 + wq * 32 + l32) * D_ +
                         h * 64 + ks * 16 + hi * 8);

    #define ATTN_STAGE(j, buf)                                                 \
        {   _Pragma("unroll")                                                  \
            for (int i = 0; i < 2; ++i) {                                      \
                async_copy16(                                                  \
                    kbase + (size_t)((j) * 64 + rowS[i]) * D_ + slS[i] * 8,    \
                    &Ks[buf][wave * 1024 + i * 512]);                          \
                async_copy16(                                                  \
                    vbase + (size_t)rowS[i] * NSEQ + (j) * 64 + slS[i] * 8,    \
                    &Vs[buf][wave * 1024 + i * 512]);                          \
            } }

    ATTN_STAGE(0, 0)
    __syncthreads();                            // vmcnt drain: tile 0 resident

    f32x16 oacc[2] = {};                        // O^T[eb*32 + crow][q], own keys
    float lacc = 0.f;

    for (int j = 0; j < NSEQ / 64; ++j) {
        const int cur = j & 1;
        if (j + 1 < NSEQ / 64) ATTN_STAGE(j + 1, 1 - cur)   // in flight over compute

        const unsigned short* Kc = Ks[cur];
        const unsigned short* Vc = Vs[cur];

        // S-block = mfma(K, Q): A = K[key = wk*32 + l32][k-octet ks*2 + hi]
        f32x16 sacc = {};
        #pragma unroll
        for (int ks = 0; ks < 4; ++ks) {
            bf16x8 kf = ld_frag(&Kc[lds_blk(wk * 32 + l32, ks * 2 + hi)]);
            sacc = __builtin_amdgcn_mfma_f32_32x32x16_bf16(kf, qf[ks], sacc, 0, 0, 0);
        }

        // exp (m=0); lane holds P for 16 keys: k_local = (r&3)+8*(r>>2)+4*hi
        float p[16];
        #pragma unroll
        for (int r = 0; r < 16; ++r) p[r] = __expf(sacc[r]);
        lacc += ((p[0] + p[1]) + (p[2] + p[3])) + ((p[4] + p[5]) + (p[6] + p[7])) +
                (((p[8] + p[9]) + (p[10] + p[11])) + ((p[12] + p[13]) + (p[14] + p[15])));

        // Build PV B-frags in-register: pack bf16 pairs, then swap lane-halves.
        #pragma unroll
        for (int s = 0; s < 2; ++s) {
            unsigned x0 = pk2(p[s * 8 + 0], p[s * 8 + 1]);
            unsigned x1 = pk2(p[s * 8 + 2], p[s * 8 + 3]);
            unsigned y0 = pk2(p[s * 8 + 4], p[s * 8 + 5]);
            unsigned y1 = pk2(p[s * 8 + 6], p[s * 8 + 7]);
            asm volatile("v_permlane32_swap_b32 %0, %1" : "+v"(x0), "+v"(y0));
            asm volatile("v_permlane32_swap_b32 %0, %1" : "+v"(x1), "+v"(y1));
            uint4 u = make_uint4(x0, x1, y0, y1);
            bf16x8 pb = __builtin_bit_cast(bf16x8, u);
            // O^T += V^T·P : A = V^T[e = eb*32 + l32][k-octet wk*4 + s*2 + hi]
            #pragma unroll
            for (int eb = 0; eb < 2; ++eb) {
                bf16x8 vf = ld_frag(&Vc[lds_blk(eb * 32 + l32, wk * 4 + s * 2 + hi)]);
                oacc[eb] = __builtin_amdgcn_mfma_f32_32x32x16_bf16(
                    vf, pb, oacc[eb], 0, 0, 0);
            }
        }

        __syncthreads();   // drains vmcnt (tile j+1 committed) + lgkm; flips buffers
    }

    // ---- epilogue: combine wk pairs through LDS (Ks/Vs dead), normalize ----
    lacc += __shfl_xor(lacc, 32);              // wave partial l(q), q = l32
    float* Of = reinterpret_cast<float*>(&Ks[0][0]);   // [wq][32 q][64 e] = 16 KB
    float* Lf = reinterpret_cast<float*>(&Vs[0][0]);   // [wq][32 q]
    if (wk == 0) {
        #pragma unroll
        for (int eb = 0; eb < 2; ++eb)
            #pragma unroll
            for (int rg = 0; rg < 4; ++rg) {
                f32x4 v = {oacc[eb][rg * 4 + 0], oacc[eb][rg * 4 + 1],
                           oacc[eb][rg * 4 + 2], oacc[eb][rg * 4 + 3]};
                *reinterpret_cast<f32x4*>(
                    &Of[(wq * 32 + l32) * 64 + eb * 32 + rg * 8 + hi * 4]) = v;
            }
        if (hi == 0) Lf[wq * 32 + l32] = lacc;
    }
    __syncthreads();
    if (wk == 1) {
        const float li = 1.0f / (lacc + Lf[wq * 32 + l32]);
        unsigned short* op =
            aob + (size_t)(b * NSEQ + n0 + wq * 32 + l32) * D_ + h * 64;
        #pragma unroll
        for (int eb = 0; eb < 2; ++eb)
            #pragma unroll
            for (int rg = 0; rg < 4; ++rg) {
                const f32x4 o = *reinterpret_cast<const f32x4*>(
                    &Of[(wq * 32 + l32) * 64 + eb * 32 + rg * 8 + hi * 4]);
                ushort4 st = make_ushort4(f2b((oacc[eb][rg * 4 + 0] + o.x) * li),
                                          f2b((oacc[eb][rg * 4 + 1] + o.y) * li),
                                          f2b((oacc[eb][rg * 4 + 2] + o.z) * li),
                                          f2b((oacc[eb][rg * 4 + 3] + o.w) * li));
                *reinterpret_cast<ushort4*>(op + eb * 32 + rg * 8 + hi * 4) = st;
            }
    }
    #undef ATTN_STAGE
}

// ---------------------------------------------------------------------------
// Output NT-GEMM: Out[m][o] = sum_d aob[m][d] * Wout[o][d]. 8192x512x512.
// 128x128 tile, BK=32, interleaved-4 LDS (32 KB) -> 3 blocks/CU; grid 256
// all-resident. fp32 direct-store epilogue.
// ---------------------------------------------------------------------------
__global__ __launch_bounds__(256, 3)
void out_gemm(const unsigned short* __restrict__ A,
              const unsigned short* __restrict__ Wo,
              float* __restrict__ Out) {
    const int m0  = blockIdx.x * 128;
    const int no0 = blockIdx.y * 128;
    const int tid = threadIdx.x;
    const int wave = tid >> 6, lane = tid & 63;
    const int quad = lane >> 4, l16 = lane & 15;
    const int wr = wave >> 1, wc = wave & 1;

    __shared__ unsigned short SM[16384];     // 32 KB
    unsigned short* Ab = SM;
    unsigned short* Bb = SM + 8192;

    const unsigned short* Ap = A + (size_t)m0 * D_;
    const unsigned short* Bp = Wo + (size_t)no0 * D_;

    int rowS[2], slS[2];
    #pragma unroll
    for (int i = 0; i < 2; ++i) STAGE_SRC32(wave * 32 + i * 16, lane, rowS[i], slS[i])

    #define OUT_STAGE(kt, buf)                                                 \
        {   _Pragma("unroll")                                                  \
            for (int i = 0; i < 2; ++i)                                        \
                async_copy16(Ap + (size_t)rowS[i] * D_ + (kt) * 32 + slS[i] * 8, \
                             Ab + (buf) * 4096 + (wave * 32 + i * 16) * 32);   \
            _Pragma("unroll")                                                  \
            for (int i = 0; i < 2; ++i)                                        \
                async_copy16(Bp + (size_t)rowS[i] * D_ + (kt) * 32 + slS[i] * 8, \
                             Bb + (buf) * 4096 + (wave * 32 + i * 16) * 32);   \
        }

    OUT_STAGE(0, 0)
    __syncthreads();

    const f32x4 z = {0.f, 0.f, 0.f, 0.f};
    f32x4 acc[4][4];
    #pragma unroll
    for (int i = 0; i < 4; ++i)
        #pragma unroll
        for (int j = 0; j < 4; ++j) acc[i][j] = z;

    for (int kt = 0; kt < 16; ++kt) {
        const int cur = kt & 1;
        if (kt + 1 < 16) OUT_STAGE(kt + 1, 1 - cur)
        bf16x8 bfr[4];
        #pragma unroll
        for (int nt = 0; nt < 4; ++nt)
            bfr[nt] = ld_frag(&Bb[cur * 4096 +
                                  lds_blk32(wc * 64 + nt * 16 + l16, quad)]);
        #pragma unroll
        for (int mt = 0; mt < 4; ++mt) {
            bf16x8 af = ld_frag(&Ab[cur * 4096 +
                                    lds_blk32(wr * 64 + mt * 16 + l16, quad)]);
            #pragma unroll
            for (int nt = 0; nt < 4; ++nt)
                acc[mt][nt] = __builtin_amdgcn_mfma_f32_16x16x32_bf16(
                    af, bfr[nt], acc[mt][nt], 0, 0, 0);
        }
        __syncthreads();
    }
    #pragma unroll
    for (int mt = 0; mt < 4; ++mt)
        #pragma unroll
        for (int nt = 0; nt < 4; ++nt)
            #pragma unroll
            for (int r = 0; r < 4; ++r)
                Out[(size_t)(m0 + wr * 64 + mt * 16 + quad * 4 + r) * D_ +
                    no0 + wc * 64 + nt * 16 + l16] = acc[mt][nt][r];
    #undef OUT_STAGE
}

// ---------------------------------------------------------------------------
extern "C" void kernel_launch(void* const* d_in, const int* in_sizes, int n_in,
                              void* d_out, int out_size, void* d_ws, size_t ws_size,
                              hipStream_t stream) {
    const float* keys   = (const float*)d_in[0];
    const float* values = (const float*)d_in[1];
    const float* query  = (const float*)d_in[2];
    const float* Wk     = (const float*)d_in[3];
    const float* Wv     = (const float*)d_in[4];
    const float* Wq     = (const float*)d_in[5];
    const float* Wout   = (const float*)d_in[6];
    float* out = (float*)d_out;

    unsigned short* ws16 = (unsigned short*)d_ws;
    const size_t XN = (size_t)B_ * NSEQ * D_;      // 4,194,304
    const size_t WN = (size_t)H_ * D_ * E_;        // 262,144
    unsigned short* wkt = ws16;                    // [he][d]
    unsigned short* wvt = wkt + WN;
    unsigned short* wqt = wvt + WN;                // pre-scaled by 1/64
    unsigned short* wob = wqt + WN;
    unsigned short* qb  = wob + WN;                // [8192][512], col=h*64+e
    unsigned short* kb  = qb + XN;                 // [8192][512]
    unsigned short* vtb = kb + XN;                 // [b][h][e][n]
    unsigned short* aob = vtb + XN;                // [8192][512] head-concat
    unsigned short* qx  = aob + XN;                // bf16 query  [8192][512]
    unsigned short* kx  = qx + XN;                 // bf16 keys   [8192][512]
    unsigned short* vx  = aob;                     // bf16 values ALIASES aob:
                                                   // vx dead after proj; aob
                                                   // written only by attn (later)

    prep_kernel<<<dim3(1024, 4), 256, 0, stream>>>(
        query, keys, values, Wk, Wv, Wq, Wout,
        qx, kx, vx, wkt, wvt, wqt, wob);

    proj_gemm<<<dim3(64, 4, 3), 256, 0, stream>>>(
        qx, kx, vx, wqt, wkt, wvt, qb, kb, vtb);

    attn_kernel<<<dim3(1024), 256, 0, stream>>>(qb, kb, vtb, aob);

    out_gemm<<<dim3(64, 4), 256, 0, stream>>>(aob, wob, out);
}

// Round 10
// 185.484 us; speedup vs baseline: 1.0811x; 1.0101x over previous
//
#include <hip/hip_runtime.h>

// B=4, H=8, Nt=Nc=2048, D=512, E=64, scale = 1/64 folded into Wq at cast.
#define B_   4
#define H_   8
#define NSEQ 2048
#define D_   512
#define E_   64

typedef __bf16 bf16x8 __attribute__((ext_vector_type(8)));
typedef float  f32x4  __attribute__((ext_vector_type(4)));
typedef float  f32x16 __attribute__((ext_vector_type(16)));

__device__ __forceinline__ unsigned short f2b(float f) {
    __bf16 h = (__bf16)f;                     // RNE
    return __builtin_bit_cast(unsigned short, h);
}
__device__ __forceinline__ unsigned pk2(float a, float b) {
    return (unsigned)f2b(a) | ((unsigned)f2b(b) << 16);
}
__device__ __forceinline__ bf16x8 ld_frag(const unsigned short* p) {
    return *reinterpret_cast<const bf16x8*>(p);
}
// async global->LDS, 16B per lane: LDS dest = wave-uniform base + lane*16.
__device__ __forceinline__ void async_copy16(const void* g, const unsigned short* l) {
    __builtin_amdgcn_global_load_lds(
        (const __attribute__((address_space(1))) unsigned int*)g,
        (__attribute__((address_space(3))) unsigned int*)l, 16, 0, 0);
}

// ---------------------------------------------------------------------------
// Interleaved-2 layout for 128-B rows (8 slots): attn K/V tiles (verified).
// ---------------------------------------------------------------------------
__device__ __forceinline__ int lds_blk(int r, int s) {
    int lr = r >> 1;
    return lr * 128 + (((((r & 1) << 3) | s) ^ (lr & 15)) << 3);  // ushort idx
}
#define STAGE_SRC(r0, l, row, slot)                                            \
    {   int lr_ = ((r0) >> 1) + ((l) >> 4);                                    \
        int B_x = ((l) & 15) ^ (lr_ & 15);                                     \
        row = (lr_ << 1) | (B_x >> 3);  slot = B_x & 7; }

// ---------------------------------------------------------------------------
// Interleaved-4 layout for 64-B rows (4 slots) — BK=32 GEMM tiles (verified
// bit-identical in round 9).
// ---------------------------------------------------------------------------
__device__ __forceinline__ int lds_blk32(int r, int s) {
    int lr = r >> 2;
    return lr * 128 + (((((r & 3) << 2) | s) ^ (lr & 15)) << 3);  // ushort idx
}
#define STAGE_SRC32(r0, l, row, slot)                                          \
    {   int lr_ = ((r0) >> 2) + ((l) >> 4);                                    \
        int B_x = ((l) & 15) ^ (lr_ & 15);                                     \
        row = (lr_ << 2) | (B_x >> 2);  slot = B_x & 3; }

// counted waits + raw barrier (T4: never drain vmcnt to 0 in the main loop)
#define WAIT_LGKM0  asm volatile("s_waitcnt lgkmcnt(0)" ::: "memory")
#define WAIT_VM(N)  asm volatile("s_waitcnt vmcnt(" #N ")" ::: "memory")
#define SCHED_FENCE __builtin_amdgcn_sched_barrier(0)
#define RAW_BARRIER __builtin_amdgcn_s_barrier()

// ---------------------------------------------------------------------------
// Fused prep: y=0..2 -> X cast fp32->bf16 (q/k/v); y=3 -> all W casts.
// (FROZEN control)
// ---------------------------------------------------------------------------
__global__ __launch_bounds__(256)
void prep_kernel(const float* __restrict__ q, const float* __restrict__ k,
                 const float* __restrict__ v,
                 const float* __restrict__ Wk, const float* __restrict__ Wv,
                 const float* __restrict__ Wq, const float* __restrict__ Wo,
                 unsigned short* __restrict__ qx, unsigned short* __restrict__ kx,
                 unsigned short* __restrict__ vx,
                 unsigned short* __restrict__ okt, unsigned short* __restrict__ ovt,
                 unsigned short* __restrict__ oqt, unsigned short* __restrict__ oo) {
    const int y = blockIdx.y;
    if (y == 3) {
        int idx = blockIdx.x * 256 + threadIdx.x;   // < 262144
        int hh = idx >> 15, rem = idx & 32767, d = rem >> 6, e = rem & 63;
        int t = hh * 32768 + e * 512 + d;            // [(h*64+e)][d]
        okt[t] = f2b(Wk[idx]);
        ovt[t] = f2b(Wv[idx]);
        oqt[t] = f2b(Wq[idx] * 0.015625f);
        oo[idx] = f2b(Wo[idx]);
        return;
    }
    const float* src = y == 0 ? q : (y == 1 ? k : v);
    unsigned short* dst = y == 0 ? qx : (y == 1 ? kx : vx);
    #pragma unroll
    for (int i = 0; i < 4; ++i) {
        int e = blockIdx.x * 4096 + i * 1024 + threadIdx.x * 4;
        float4 f = *reinterpret_cast<const float4*>(src + e);
        *reinterpret_cast<ushort4*>(dst + e) =
            make_ushort4(f2b(f.x), f2b(f.y), f2b(f.z), f2b(f.w));
    }
}

// ---------------------------------------------------------------------------
// Projection NT-GEMM (pure bf16): C[m][he] = sum_d X[m][d]*Wt[he][d].
// 8192x512x512, which: 0=Q 1=K 2=V. 128x128 tile, BK=32, interleaved-4 LDS.
// ROUND 10: depth-3 pipeline, TRIPLE-buffered LDS (48 KB -> 3 blocks/CU),
// counted s_waitcnt vmcnt(4) + raw s_barrier — loads for tile kt+2 stay in
// flight ACROSS the barrier (T4); the old per-iter vmcnt(0) drain is gone.
// Accumulation order identical -> bit-identical output (tripwire).
// ---------------------------------------------------------------------------
__global__ __launch_bounds__(256, 3)
void proj_gemm(const unsigned short* __restrict__ qx,
               const unsigned short* __restrict__ kx,
               const unsigned short* __restrict__ vx,
               const unsigned short* __restrict__ wqt,
               const unsigned short* __restrict__ wkt,
               const unsigned short* __restrict__ wvt,
               unsigned short* __restrict__ qb, unsigned short* __restrict__ kb,
               unsigned short* __restrict__ vtb) {
    const int m0  = blockIdx.x * 128;
    const int no0 = blockIdx.y * 128;
    const int which = blockIdx.z;
    const int tid = threadIdx.x;
    const int wave = tid >> 6, lane = tid & 63;
    const int quad = lane >> 4, l16 = lane & 15;
    const int wr = wave >> 1, wc = wave & 1;

    const unsigned short* X = which == 0 ? qx : (which == 1 ? kx : vx);
    const unsigned short* W = which == 0 ? wqt : (which == 1 ? wkt : wvt);

    __shared__ unsigned short SM[24576];     // 48 KB: 3 x (A 8KB + B 8KB)
    unsigned short* Ab = SM;                 // [3][128 r][32 d] interleaved-4
    unsigned short* Bb = SM + 12288;         // [3][128 r][32 d] interleaved-4

    const unsigned short* Xp = X + (size_t)m0 * D_;
    const unsigned short* Wp = W + (size_t)no0 * D_;

    // per-lane staging source (loop-invariant): 2 slabs of 16 rows per wave
    int rowS[2], slS[2];
    #pragma unroll
    for (int i = 0; i < 2; ++i) STAGE_SRC32(wave * 32 + i * 16, lane, rowS[i], slS[i])

    // 4 async_copy16 per wave per tile (2 A + 2 B)
    #define PROJ_STAGE(kt, buf)                                                \
        {   _Pragma("unroll")                                                  \
            for (int i = 0; i < 2; ++i)                                        \
                async_copy16(Xp + (size_t)rowS[i] * D_ + (kt) * 32 + slS[i] * 8, \
                             Ab + (buf) * 4096 + (wave * 32 + i * 16) * 32);   \
            _Pragma("unroll")                                                  \
            for (int i = 0; i < 2; ++i)                                        \
                async_copy16(Wp + (size_t)rowS[i] * D_ + (kt) * 32 + slS[i] * 8, \
                             Bb + (buf) * 4096 + (wave * 32 + i * 16) * 32);   \
        }

    PROJ_STAGE(0, 0)                          // outstanding 4
    PROJ_STAGE(1, 1)                          // outstanding 8
    WAIT_VM(4);                               // tile 0 resident (tile 1 in flight)
    SCHED_FENCE;
    RAW_BARRIER;
    SCHED_FENCE;

    const f32x4 z = {0.f, 0.f, 0.f, 0.f};
    f32x4 acc[4][4];
    #pragma unroll
    for (int i = 0; i < 4; ++i)
        #pragma unroll
        for (int j = 0; j < 4; ++j) acc[i][j] = z;

    #pragma unroll
    for (int kt = 0; kt < 16; ++kt) {
        const int cur = kt % 3;
        if (kt + 2 < 16) PROJ_STAGE(kt + 2, (kt + 2) % 3)  // overwrites buf read
                                                           // at iter kt-1 (safe:
                                                           // barrier'd since)
        bf16x8 bfr[4];
        #pragma unroll
        for (int nt = 0; nt < 4; ++nt)
            bfr[nt] = ld_frag(&Bb[cur * 4096 +
                                  lds_blk32(wc * 64 + nt * 16 + l16, quad)]);
        #pragma unroll
        for (int mt = 0; mt < 4; ++mt) {
            bf16x8 af = ld_frag(&Ab[cur * 4096 +
                                    lds_blk32(wr * 64 + mt * 16 + l16, quad)]);
            #pragma unroll
            for (int nt = 0; nt < 4; ++nt)
                acc[mt][nt] = __builtin_amdgcn_mfma_f32_16x16x32_bf16(
                    af, bfr[nt], acc[mt][nt], 0, 0, 0);
        }
        WAIT_LGKM0;                    // my ds_reads of tile kt retired
        if (kt + 2 < 16)      { WAIT_VM(4); }  // tile kt+1 landed; kt+2 flying
        else if (kt + 1 < 16) { WAIT_VM(0); }  // last prefetched tile
        SCHED_FENCE;
        RAW_BARRIER;                   // all waves: reads done, next tile ready
        SCHED_FENCE;
    }

    // epilogue: two-chunk restage through SM (tiles dead; 48 KB available)
    if (which != 2) {
        unsigned short* Y = (which == 0 ? qb : kb);
        unsigned short (*Os)[136] = reinterpret_cast<unsigned short(*)[136]>(SM);
        #pragma unroll
        for (int h = 0; h < 2; ++h) {          // chunk = m-rows [h*64, h*64+64)
            if (wr == h) {
                #pragma unroll
                for (int mt = 0; mt < 4; ++mt)
                    #pragma unroll
                    for (int nt = 0; nt < 4; ++nt)
                        #pragma unroll
                        for (int r = 0; r < 4; ++r)
                            Os[mt * 16 + quad * 4 + r][wc * 64 + nt * 16 + l16] =
                                f2b(acc[mt][nt][r]);
            }
            __syncthreads();
            #pragma unroll
            for (int i = 0; i < 4; ++i) {      // 64 rows x 16 uint4
                int idx = tid + i * 256;
                int row = idx >> 4, seg = idx & 15;
                *reinterpret_cast<uint4*>(
                    Y + (size_t)(m0 + h * 64 + row) * D_ + no0 + seg * 8) =
                    *reinterpret_cast<const uint4*>(&Os[row][seg * 8]);
            }
            if (h == 0) __syncthreads();
        }
    } else {
        unsigned short (*Ot)[144] = reinterpret_cast<unsigned short(*)[144]>(SM);
        const int b = m0 >> 11, nloc = m0 & 2047;
        #pragma unroll
        for (int h = 0; h < 2; ++h) {          // chunk = he-rows [h*64, h*64+64)
            if (wc == h) {
                #pragma unroll
                for (int mt = 0; mt < 4; ++mt)
                    #pragma unroll
                    for (int nt = 0; nt < 4; ++nt) {
                        ushort4 o = make_ushort4(
                            f2b(acc[mt][nt][0]), f2b(acc[mt][nt][1]),
                            f2b(acc[mt][nt][2]), f2b(acc[mt][nt][3]));
                        *reinterpret_cast<ushort4*>(
                            &Ot[nt * 16 + l16][wr * 64 + mt * 16 + quad * 4]) = o;
                    }
            }
            __syncthreads();
            #pragma unroll
            for (int i = 0; i < 4; ++i) {      // 64 he-rows x 16 uint4
                int idx = tid + i * 256;
                int lhe = idx >> 4, seg = idx & 15;
                int ghe = no0 + h * 64 + lhe;  // h = ghe>>6, e = ghe&63
                *reinterpret_cast<uint4*>(
                    vtb + ((size_t)(b * H_ + (ghe >> 6)) * E_ + (ghe & 63)) * NSEQ +
                    nloc + seg * 8) =
                    *reinterpret_cast<const uint4*>(&Ot[lhe][seg * 8]);
            }
            if (h == 0) __syncthreads();
        }
    }
    #undef PROJ_STAGE
}

// ---------------------------------------------------------------------------
// Flash attention (round-6 best, FROZEN: ~58 us). 32x32x16 MFMA,
// in-register P (permlane), interleaved-2 conflict-free LDS, 32 KB.
// ---------------------------------------------------------------------------
__global__ __launch_bounds__(256, 3)
void attn_kernel(const unsigned short* __restrict__ qbp,
                 const unsigned short* __restrict__ kbp,
                 const unsigned short* __restrict__ vtbp,
                 unsigned short* __restrict__ aob) {
    const int L = blockIdx.x;
    const int bh = L & 31, qt = L >> 5;      // L%8 pattern -> XCD K/V affinity
    const int b = bh >> 3, h = bh & 7;
    const int n0 = qt * 64;
    const int tid = threadIdx.x;
    const int wave = tid >> 6, lane = tid & 63;
    const int wk = wave >> 1, wq = wave & 1;
    const int l32 = lane & 31, hi = lane >> 5;

    __shared__ unsigned short Ks[2][4096];   // 16 KiB (dbuf K, 64 rows)
    __shared__ unsigned short Vs[2][4096];   // 16 KiB (dbuf V^T, 64 e-rows)

    const unsigned short* kbase = kbp + (size_t)(b * NSEQ) * D_ + h * 64;
    const unsigned short* vbase = vtbp + (size_t)(b * H_ + h) * E_ * NSEQ;

    int rowS[2], slS[2];
    #pragma unroll
    for (int i = 0; i < 2; ++i) STAGE_SRC(wave * 16 + i * 8, lane, rowS[i], slS[i])

    // Q B-frags (32x32x16 B layout: lane&31 = q col, k-octet = hi):
    bf16x8 qf[4];
    #pragma unroll
    for (int ks = 0; ks < 4; ++ks)
        qf[ks] = ld_frag(qbp + (size_t)(b * NSEQ + n0 + wq * 32 + l32) * D_ +
                         h * 64 + ks * 16 + hi * 8);

    #define ATTN_STAGE(j, buf)                                                 \
        {   _Pragma("unroll")                                                  \
            for (int i = 0; i < 2; ++i) {                                      \
                async_copy16(                                                  \
                    kbase + (size_t)((j) * 64 + rowS[i]) * D_ + slS[i] * 8,    \
                    &Ks[buf][wave * 1024 + i * 512]);                          \
                async_copy16(                                                  \
                    vbase + (size_t)rowS[i] * NSEQ + (j) * 64 + slS[i] * 8,    \
                    &Vs[buf][wave * 1024 + i * 512]);                          \
            } }

    ATTN_STAGE(0, 0)
    __syncthreads();                            // vmcnt drain: tile 0 resident

    f32x16 oacc[2] = {};                        // O^T[eb*32 + crow][q], own keys
    float lacc = 0.f;

    for (int j = 0; j < NSEQ / 64; ++j) {
        const int cur = j & 1;
        if (j + 1 < NSEQ / 64) ATTN_STAGE(j + 1, 1 - cur)   // in flight over compute

        const unsigned short* Kc = Ks[cur];
        const unsigned short* Vc = Vs[cur];

        // S-block = mfma(K, Q): A = K[key = wk*32 + l32][k-octet ks*2 + hi]
        f32x16 sacc = {};
        #pragma unroll
        for (int ks = 0; ks < 4; ++ks) {
            bf16x8 kf = ld_frag(&Kc[lds_blk(wk * 32 + l32, ks * 2 + hi)]);
            sacc = __builtin_amdgcn_mfma_f32_32x32x16_bf16(kf, qf[ks], sacc, 0, 0, 0);
        }

        // exp (m=0); lane holds P for 16 keys: k_local = (r&3)+8*(r>>2)+4*hi
        float p[16];
        #pragma unroll
        for (int r = 0; r < 16; ++r) p[r] = __expf(sacc[r]);
        lacc += ((p[0] + p[1]) + (p[2] + p[3])) + ((p[4] + p[5]) + (p[6] + p[7])) +
                (((p[8] + p[9]) + (p[10] + p[11])) + ((p[12] + p[13]) + (p[14] + p[15])));

        // Build PV B-frags in-register: pack bf16 pairs, then swap lane-halves.
        #pragma unroll
        for (int s = 0; s < 2; ++s) {
            unsigned x0 = pk2(p[s * 8 + 0], p[s * 8 + 1]);
            unsigned x1 = pk2(p[s * 8 + 2], p[s * 8 + 3]);
            unsigned y0 = pk2(p[s * 8 + 4], p[s * 8 + 5]);
            unsigned y1 = pk2(p[s * 8 + 6], p[s * 8 + 7]);
            asm volatile("v_permlane32_swap_b32 %0, %1" : "+v"(x0), "+v"(y0));
            asm volatile("v_permlane32_swap_b32 %0, %1" : "+v"(x1), "+v"(y1));
            uint4 u = make_uint4(x0, x1, y0, y1);
            bf16x8 pb = __builtin_bit_cast(bf16x8, u);
            // O^T += V^T·P : A = V^T[e = eb*32 + l32][k-octet wk*4 + s*2 + hi]
            #pragma unroll
            for (int eb = 0; eb < 2; ++eb) {
                bf16x8 vf = ld_frag(&Vc[lds_blk(eb * 32 + l32, wk * 4 + s * 2 + hi)]);
                oacc[eb] = __builtin_amdgcn_mfma_f32_32x32x16_bf16(
                    vf, pb, oacc[eb], 0, 0, 0);
            }
        }

        __syncthreads();   // drains vmcnt (tile j+1 committed) + lgkm; flips buffers
    }

    // ---- epilogue: combine wk pairs through LDS (Ks/Vs dead), normalize ----
    lacc += __shfl_xor(lacc, 32);              // wave partial l(q), q = l32
    float* Of = reinterpret_cast<float*>(&Ks[0][0]);   // [wq][32 q][64 e] = 16 KB
    float* Lf = reinterpret_cast<float*>(&Vs[0][0]);   // [wq][32 q]
    if (wk == 0) {
        #pragma unroll
        for (int eb = 0; eb < 2; ++eb)
            #pragma unroll
            for (int rg = 0; rg < 4; ++rg) {
                f32x4 v = {oacc[eb][rg * 4 + 0], oacc[eb][rg * 4 + 1],
                           oacc[eb][rg * 4 + 2], oacc[eb][rg * 4 + 3]};
                *reinterpret_cast<f32x4*>(
                    &Of[(wq * 32 + l32) * 64 + eb * 32 + rg * 8 + hi * 4]) = v;
            }
        if (hi == 0) Lf[wq * 32 + l32] = lacc;
    }
    __syncthreads();
    if (wk == 1) {
        const float li = 1.0f / (lacc + Lf[wq * 32 + l32]);
        unsigned short* op =
            aob + (size_t)(b * NSEQ + n0 + wq * 32 + l32) * D_ + h * 64;
        #pragma unroll
        for (int eb = 0; eb < 2; ++eb)
            #pragma unroll
            for (int rg = 0; rg < 4; ++rg) {
                const f32x4 o = *reinterpret_cast<const f32x4*>(
                    &Of[(wq * 32 + l32) * 64 + eb * 32 + rg * 8 + hi * 4]);
                ushort4 st = make_ushort4(f2b((oacc[eb][rg * 4 + 0] + o.x) * li),
                                          f2b((oacc[eb][rg * 4 + 1] + o.y) * li),
                                          f2b((oacc[eb][rg * 4 + 2] + o.z) * li),
                                          f2b((oacc[eb][rg * 4 + 3] + o.w) * li));
                *reinterpret_cast<ushort4*>(op + eb * 32 + rg * 8 + hi * 4) = st;
            }
    }
    #undef ATTN_STAGE
}

// ---------------------------------------------------------------------------
// Output NT-GEMM: Out[m][o] = sum_d aob[m][d] * Wout[o][d]. 8192x512x512.
// 128x128 tile, BK=32. ROUND 10: same depth-3 counted-vmcnt pipeline as
// proj_gemm. fp32 direct-store epilogue.
// ---------------------------------------------------------------------------
__global__ __launch_bounds__(256, 3)
void out_gemm(const unsigned short* __restrict__ A,
              const unsigned short* __restrict__ Wo,
              float* __restrict__ Out) {
    const int m0  = blockIdx.x * 128;
    const int no0 = blockIdx.y * 128;
    const int tid = threadIdx.x;
    const int wave = tid >> 6, lane = tid & 63;
    const int quad = lane >> 4, l16 = lane & 15;
    const int wr = wave >> 1, wc = wave & 1;

    __shared__ unsigned short SM[24576];     // 48 KB: 3 x (A 8KB + B 8KB)
    unsigned short* Ab = SM;
    unsigned short* Bb = SM + 12288;

    const unsigned short* Ap = A + (size_t)m0 * D_;
    const unsigned short* Bp = Wo + (size_t)no0 * D_;

    int rowS[2], slS[2];
    #pragma unroll
    for (int i = 0; i < 2; ++i) STAGE_SRC32(wave * 32 + i * 16, lane, rowS[i], slS[i])

    #define OUT_STAGE(kt, buf)                                                 \
        {   _Pragma("unroll")                                                  \
            for (int i = 0; i < 2; ++i)                                        \
                async_copy16(Ap + (size_t)rowS[i] * D_ + (kt) * 32 + slS[i] * 8, \
                             Ab + (buf) * 4096 + (wave * 32 + i * 16) * 32);   \
            _Pragma("unroll")                                                  \
            for (int i = 0; i < 2; ++i)                                        \
                async_copy16(Bp + (size_t)rowS[i] * D_ + (kt) * 32 + slS[i] * 8, \
                             Bb + (buf) * 4096 + (wave * 32 + i * 16) * 32);   \
        }

    OUT_STAGE(0, 0)
    OUT_STAGE(1, 1)
    WAIT_VM(4);
    SCHED_FENCE;
    RAW_BARRIER;
    SCHED_FENCE;

    const f32x4 z = {0.f, 0.f, 0.f, 0.f};
    f32x4 acc[4][4];
    #pragma unroll
    for (int i = 0; i < 4; ++i)
        #pragma unroll
        for (int j = 0; j < 4; ++j) acc[i][j] = z;

    #pragma unroll
    for (int kt = 0; kt < 16; ++kt) {
        const int cur = kt % 3;
        if (kt + 2 < 16) OUT_STAGE(kt + 2, (kt + 2) % 3)
        bf16x8 bfr[4];
        #pragma unroll
        for (int nt = 0; nt < 4; ++nt)
            bfr[nt] = ld_frag(&Bb[cur * 4096 +
                                  lds_blk32(wc * 64 + nt * 16 + l16, quad)]);
        #pragma unroll
        for (int mt = 0; mt < 4; ++mt) {
            bf16x8 af = ld_frag(&Ab[cur * 4096 +
                                    lds_blk32(wr * 64 + mt * 16 + l16, quad)]);
            #pragma unroll
            for (int nt = 0; nt < 4; ++nt)
                acc[mt][nt] = __builtin_amdgcn_mfma_f32_16x16x32_bf16(
                    af, bfr[nt], acc[mt][nt], 0, 0, 0);
        }
        WAIT_LGKM0;
        if (kt + 2 < 16)      { WAIT_VM(4); }
        else if (kt + 1 < 16) { WAIT_VM(0); }
        SCHED_FENCE;
        RAW_BARRIER;
        SCHED_FENCE;
    }
    #pragma unroll
    for (int mt = 0; mt < 4; ++mt)
        #pragma unroll
        for (int nt = 0; nt < 4; ++nt)
            #pragma unroll
            for (int r = 0; r < 4; ++r)
                Out[(size_t)(m0 + wr * 64 + mt * 16 + quad * 4 + r) * D_ +
                    no0 + wc * 64 + nt * 16 + l16] = acc[mt][nt][r];
    #undef OUT_STAGE
}

// ---------------------------------------------------------------------------
extern "C" void kernel_launch(void* const* d_in, const int* in_sizes, int n_in,
                              void* d_out, int out_size, void* d_ws, size_t ws_size,
                              hipStream_t stream) {
    const float* keys   = (const float*)d_in[0];
    const float* values = (const float*)d_in[1];
    const float* query  = (const float*)d_in[2];
    const float* Wk     = (const float*)d_in[3];
    const float* Wv     = (const float*)d_in[4];
    const float* Wq     = (const float*)d_in[5];
    const float* Wout   = (const float*)d_in[6];
    float* out = (float*)d_out;

    unsigned short* ws16 = (unsigned short*)d_ws;
    const size_t XN = (size_t)B_ * NSEQ * D_;      // 4,194,304
    const size_t WN = (size_t)H_ * D_ * E_;        // 262,144
    unsigned short* wkt = ws16;                    // [he][d]
    unsigned short* wvt = wkt + WN;
    unsigned short* wqt = wvt + WN;                // pre-scaled by 1/64
    unsigned short* wob = wqt + WN;
    unsigned short* qb  = wob + WN;                // [8192][512], col=h*64+e
    unsigned short* kb  = qb + XN;                 // [8192][512]
    unsigned short* vtb = kb + XN;                 // [b][h][e][n]
    unsigned short* aob = vtb + XN;                // [8192][512] head-concat
    unsigned short* qx  = aob + XN;                // bf16 query  [8192][512]
    unsigned short* kx  = qx + XN;                 // bf16 keys   [8192][512]
    unsigned short* vx  = aob;                     // bf16 values ALIASES aob:
                                                   // vx dead after proj; aob
                                                   // written only by attn (later)

    prep_kernel<<<dim3(1024, 4), 256, 0, stream>>>(
        query, keys, values, Wk, Wv, Wq, Wout,
        qx, kx, vx, wkt, wvt, wqt, wob);

    proj_gemm<<<dim3(64, 4, 3), 256, 0, stream>>>(
        qx, kx, vx, wqt, wkt, wvt, qb, kb, vtb);

    attn_kernel<<<dim3(1024), 256, 0, stream>>>(qb, kb, vtb, aob);

    out_gemm<<<dim3(64, 4), 256, 0, stream>>>(aob, wob, out);
}